// Round 2
// baseline (1932.221 us; speedup 1.0000x reference)
//
#include <hip/hip_runtime.h>

// DiT block, B=4 N=512 D=1024 H=16 HD=64 HID=4096 RP_HID=64
// All float tensors are f32 (per reference dtypes); agent_mask int32.
// Workspace (f32 floats): mod 24576 | xn 2097152 | xm 2097152 | R 8388608
//   R holds q/k/v (3x2097152) during attention, then hb (8388608) for MLP.
// Peak = 12,607,488 floats = 50.4 MB.

#define B_ 4
#define N_ 512
#define D_ 1024
#define H_ 16
#define HD_ 64
#define HID_ 4096
#define M_ (B_*N_)

// ---------------- adaLN modulation: mod[b, 0:6D] = silu(t_emb[b]) @ w_ada^T + b_ada
__global__ __launch_bounds__(256) void k_mod(const float* __restrict__ t_emb,
    const float* __restrict__ w_ada, const float* __restrict__ b_ada,
    float* __restrict__ mod)
{
  __shared__ float st[D_];
  int b = blockIdx.y;
  for (int i = threadIdx.x; i < D_; i += 256){
    float x = t_emb[b*D_ + i];
    st[i] = x / (1.f + __expf(-x));
  }
  __syncthreads();
  int j = blockIdx.x * 256 + threadIdx.x;   // 0..6143
  const float* wr = w_ada + (size_t)j * D_;
  float acc = b_ada[j];
  for (int k = 0; k < D_; k += 8){
    float4 p0 = *(const float4*)(wr + k);
    float4 p1 = *(const float4*)(wr + k + 4);
    acc += p0.x*st[k+0] + p0.y*st[k+1] + p0.z*st[k+2] + p0.w*st[k+3];
    acc += p1.x*st[k+4] + p1.y*st[k+5] + p1.z*st[k+6] + p1.w*st[k+7];
  }
  mod[b*6*D_ + j] = acc;
}

// ---------------- LayerNorm + adaLN modulate -> f32 xn
__global__ __launch_bounds__(256) void k_lnmod(const float* __restrict__ xin,
    const float* __restrict__ g, const float* __restrict__ be,
    const float* __restrict__ mod, int shift_idx, int scale_idx,
    float* __restrict__ xn)
{
  int row = blockIdx.x;          // b*N + n
  int b = row >> 9;
  float v[4]; float s = 0.f, s2 = 0.f;
  #pragma unroll
  for (int i=0;i<4;i++){
    float x = xin[(size_t)row*D_ + threadIdx.x + i*256];
    v[i] = x; s += x; s2 += x*x;
  }
  #pragma unroll
  for (int o=32;o>0;o>>=1){ s += __shfl_down(s,o); s2 += __shfl_down(s2,o); }
  __shared__ float rs[4], rs2[4];
  int w = threadIdx.x >> 6;
  if ((threadIdx.x & 63)==0){ rs[w]=s; rs2[w]=s2; }
  __syncthreads();
  s = rs[0]+rs[1]+rs[2]+rs[3]; s2 = rs2[0]+rs2[1]+rs2[2]+rs2[3];
  float mu = s * (1.f/D_);
  float var = s2 * (1.f/D_) - mu*mu;
  float rstd = rsqrtf(var + 1e-5f);
  const float* mrow = mod + b*6*D_;
  #pragma unroll
  for (int i=0;i<4;i++){
    int d = threadIdx.x + i*256;
    float xg = (v[i]-mu)*rstd*g[d] + be[d];
    xn[(size_t)row*D_ + d] = xg * (1.f + mrow[scale_idx*D_ + d]) + mrow[shift_idx*D_ + d];
  }
}

// ---------------- generic C = A(f32,[M,K]) @ W(f32,[NO,K])^T + bias, fused epilogues
enum { EPI_QKV=0, EPI_PROJ=1, EPI_FC1=2, EPI_FC2=3 };

template<int EPI>
__global__ __launch_bounds__(256) void k_gemm(const float* __restrict__ A,
    const float* __restrict__ W, const float* __restrict__ Wb,
    int K,
    const float* __restrict__ mod, const float* __restrict__ resid,
    float* __restrict__ o0, float* __restrict__ o1, float* __restrict__ o2)
{
  __shared__ __align__(16) float As[16][64];
  __shared__ __align__(16) float Ws[16][64];
  int row0 = blockIdx.y * 64, col0 = blockIdx.x * 64;
  int tid = threadIdx.x;
  int lm = tid & 63, lk = (tid >> 6) << 2;
  int tx = tid & 15, ty = tid >> 4;
  float acc[4][4] = {};
  const float* Ap = A + (size_t)(row0 + lm)*K + lk;
  const float* Wp = W + (size_t)(col0 + lm)*K + lk;
  for (int k0 = 0; k0 < K; k0 += 16){
    float4 av = *(const float4*)(Ap + k0);
    float4 wv = *(const float4*)(Wp + k0);
    As[lk+0][lm]=av.x; As[lk+1][lm]=av.y; As[lk+2][lm]=av.z; As[lk+3][lm]=av.w;
    Ws[lk+0][lm]=wv.x; Ws[lk+1][lm]=wv.y; Ws[lk+2][lm]=wv.z; Ws[lk+3][lm]=wv.w;
    __syncthreads();
    #pragma unroll
    for (int kk=0; kk<16; kk++){
      float4 a4 = *(const float4*)&As[kk][ty<<2];
      float4 w4 = *(const float4*)&Ws[kk][tx<<2];
      acc[0][0] += a4.x*w4.x; acc[0][1] += a4.x*w4.y; acc[0][2] += a4.x*w4.z; acc[0][3] += a4.x*w4.w;
      acc[1][0] += a4.y*w4.x; acc[1][1] += a4.y*w4.y; acc[1][2] += a4.y*w4.z; acc[1][3] += a4.y*w4.w;
      acc[2][0] += a4.z*w4.x; acc[2][1] += a4.z*w4.y; acc[2][2] += a4.z*w4.z; acc[2][3] += a4.z*w4.w;
      acc[3][0] += a4.w*w4.x; acc[3][1] += a4.w*w4.y; acc[3][2] += a4.w*w4.z; acc[3][3] += a4.w*w4.w;
    }
    __syncthreads();
  }
  #pragma unroll
  for (int i=0;i<4;i++){
    int r = row0 + (ty<<2) + i;
    int b = r >> 9;
    #pragma unroll
    for (int j=0;j<4;j++){
      int c = col0 + (tx<<2) + j;
      float val = acc[i][j] + Wb[c];
      if (EPI == EPI_QKV){
        int s = c >> 10, rem = c & 1023;
        if (s == 0){
          o0[(size_t)r*D_ + rem] = val;           // q as [row, h*64+hd]
        } else {
          int h = rem >> 6, hd = rem & 63;
          int n = r & 511;
          float* dst = (s == 1) ? o1 : o2;        // k/v as [B,H,N,HD]
          dst[((((size_t)b*H_ + h)*N_ + n)<<6) + hd] = val;
        }
      } else if (EPI == EPI_PROJ){
        float gte = mod[b*6*D_ + 2*D_ + c];
        o0[(size_t)r*D_ + c] = resid[(size_t)r*D_ + c] + gte * val;
      } else if (EPI == EPI_FC1){
        o0[(size_t)r*HID_ + c] = 0.5f*val*(1.f + erff(val*0.70710678f));
      } else {
        float gte = mod[b*6*D_ + 5*D_ + c];
        o0[(size_t)r*D_ + c] = resid[(size_t)r*D_ + c] + gte * val;
      }
    }
  }
}

// ---------------- attention: one block per (b, n); all 16 heads; rel-pos bias fused
__global__ __launch_bounds__(256) void k_attn(const float* __restrict__ q,
    const float* __restrict__ kx, const float* __restrict__ vx,
    const float* __restrict__ rel_pos, const int* __restrict__ agent_mask,
    const float* __restrict__ w_rp1, const float* __restrict__ b_rp1,
    const float* __restrict__ w_rp2, const float* __restrict__ b_rp2,
    float* __restrict__ attn_out)
{
  int row = blockIdx.x;          // b*N + n
  int b = row >> 9;
  int tid = threadIdx.x;
  __shared__ float sc[H_][N_];   // 32 KB
  __shared__ float qrow[D_];     // 4 KB
  __shared__ float w1[128], bb1[64], w2[H_*64], bb2[H_];
  for (int i=tid; i<128; i+=256) w1[i] = w_rp1[i];
  if (tid < 64) bb1[tid] = b_rp1[tid];
  for (int i=tid; i<H_*64; i+=256) w2[i] = w_rp2[i];
  if (tid < H_) bb2[tid] = b_rp2[tid];
  for (int i=tid; i<D_; i+=256) qrow[i] = q[(size_t)row*D_ + i];
  __syncthreads();

  // scores + rel-pos bias + mask
  for (int m = tid; m < N_; m += 256){
    float2 r01 = *(const float2*)(rel_pos + ((size_t)row*N_ + m)*2);
    float hid[64];
    #pragma unroll
    for (int j=0;j<64;j++){
      float t = w1[2*j]*r01.x + w1[2*j+1]*r01.y + bb1[j];
      hid[j] = t > 0.f ? t : 0.f;
    }
    bool valid = agent_mask[b*N_ + m] != 0;
    for (int h=0; h<H_; h++){
      float bias = bb2[h];
      #pragma unroll
      for (int j=0;j<64;j++) bias += hid[j]*w2[h*64+j];
      const float* kr = kx + ((((size_t)b*H_ + h)*N_ + m)<<6);
      float dot = 0.f;
      #pragma unroll
      for (int d=0; d<64; d+=4){
        float4 k4 = *(const float4*)(kr + d);
        dot += qrow[h*64+d+0]*k4.x + qrow[h*64+d+1]*k4.y
             + qrow[h*64+d+2]*k4.z + qrow[h*64+d+3]*k4.w;
      }
      sc[h][m] = valid ? (dot * 0.125f + bias) : -1e30f;
    }
  }
  __syncthreads();

  // softmax per head: 16 groups of 16 lanes
  {
    int h = tid >> 4, lt = tid & 15;
    float mx = -1e30f;
    for (int m = lt; m < N_; m += 16) mx = fmaxf(mx, sc[h][m]);
    #pragma unroll
    for (int o=8;o>0;o>>=1) mx = fmaxf(mx, __shfl_xor(mx, o, 16));
    float sum = 0.f;
    for (int m = lt; m < N_; m += 16){
      float e = __expf(sc[h][m] - mx);
      sc[h][m] = e; sum += e;
    }
    #pragma unroll
    for (int o=8;o>0;o>>=1) sum += __shfl_xor(sum, o, 16);
    float inv = 1.f / sum;
    for (int m = lt; m < N_; m += 16) sc[h][m] *= inv;
  }
  __syncthreads();

  // P @ V
  float acc[4] = {0.f,0.f,0.f,0.f};
  const float* vp[4]; int hh[4];
  #pragma unroll
  for (int it=0; it<4; it++){
    int e = tid + it*256;
    int h = e >> 6, d = e & 63;
    hh[it] = h;
    vp[it] = vx + ((((size_t)b*H_ + h)*N_)<<6) + d;
  }
  for (int m=0; m<N_; m++){
    #pragma unroll
    for (int it=0; it<4; it++)
      acc[it] += sc[hh[it]][m] * vp[it][(size_t)m<<6];
  }
  #pragma unroll
  for (int it=0; it<4; it++)
    attn_out[(size_t)row*D_ + tid + it*256] = acc[it];
}

extern "C" void kernel_launch(void* const* d_in, const int* in_sizes, int n_in,
                              void* d_out, int out_size, void* d_ws, size_t ws_size,
                              hipStream_t stream) {
  const float* x      = (const float*)d_in[0];
  const float* t_emb  = (const float*)d_in[1];
  const float* rel    = (const float*)d_in[2];
  const int*   amask  = (const int*)d_in[3];
  const float* w_ada  = (const float*)d_in[4];
  const float* b_ada  = (const float*)d_in[5];
  const float* g1     = (const float*)d_in[6];
  const float* beta1  = (const float*)d_in[7];
  const float* g2     = (const float*)d_in[8];
  const float* beta2  = (const float*)d_in[9];
  const float* w_qkv  = (const float*)d_in[10];
  const float* b_qkv  = (const float*)d_in[11];
  const float* w_proj = (const float*)d_in[12];
  const float* b_proj = (const float*)d_in[13];
  const float* w_rp1  = (const float*)d_in[14];
  const float* b_rp1  = (const float*)d_in[15];
  const float* w_rp2  = (const float*)d_in[16];
  const float* b_rp2  = (const float*)d_in[17];
  const float* w_fc1  = (const float*)d_in[18];
  const float* b_fc1  = (const float*)d_in[19];
  const float* w_fc2  = (const float*)d_in[20];
  const float* b_fc2  = (const float*)d_in[21];
  float* outp = (float*)d_out;

  float* ws  = (float*)d_ws;
  float* mod = ws;                         // 24576
  float* xn  = mod + 6*D_*B_;              // 2097152 (reused: attn_out, xn2)
  float* xm  = xn  + (size_t)M_*D_;        // 2097152
  float* qb  = xm  + (size_t)M_*D_;        // region R start
  float* kb  = qb  + (size_t)M_*D_;
  float* vb  = kb  + (size_t)M_*D_;
  float* hb  = qb;                         // alias over q/k/v (+2M more) = 8388608

  // 1) adaLN modulation
  k_mod<<<dim3(6*D_/256, B_), 256, 0, stream>>>(t_emb, w_ada, b_ada, mod);
  // 2) LN1 + modulate
  k_lnmod<<<M_, 256, 0, stream>>>(x, g1, beta1, mod, 0, 1, xn);
  // 3) QKV gemm (scatter q:[row,D], k/v:[B,H,N,HD])
  k_gemm<EPI_QKV><<<dim3(3*D_/64, M_/64), 256, 0, stream>>>(
      xn, w_qkv, b_qkv, D_, nullptr, nullptr, qb, kb, vb);
  // 4) attention (writes attn_out into xn)
  k_attn<<<M_, 256, 0, stream>>>(qb, kb, vb, rel, amask,
      w_rp1, b_rp1, w_rp2, b_rp2, xn);
  // 5) proj + gate_s + residual -> x_mid
  k_gemm<EPI_PROJ><<<dim3(D_/64, M_/64), 256, 0, stream>>>(
      xn, w_proj, b_proj, D_, mod, x, xm, nullptr, nullptr);
  // 6) LN2 + modulate (xn reused)
  k_lnmod<<<M_, 256, 0, stream>>>(xm, g2, beta2, mod, 3, 4, xn);
  // 7) fc1 + exact GELU -> hb (aliases dead q/k/v)
  k_gemm<EPI_FC1><<<dim3(HID_/64, M_/64), 256, 0, stream>>>(
      xn, w_fc1, b_fc1, D_, nullptr, nullptr, hb, nullptr, nullptr);
  // 8) fc2 + gate_m + residual -> f32 out
  k_gemm<EPI_FC2><<<dim3(D_/64, M_/64), 256, 0, stream>>>(
      hb, w_fc2, b_fc2, HID_, mod, xm, outp, nullptr, nullptr);
}

// Round 3
// 588.696 us; speedup vs baseline: 3.2822x; 3.2822x over previous
//
#include <hip/hip_runtime.h>

// DiT block, B=4 N=512 D=1024 H=16 HD=64 HID=4096 RP_HID=64. All f32 I/O.
// R2: MFMA everywhere. qkv/bias/h stored bf16. Flash attention w/ online softmax.
// ws layout (f32 slots): mod 24576 | xn 2097152 | xm 2097152 | qkv(u16) 3145728
//   | bias(u16) 8388608  => 15.75M floats = 63 MB. hb(u16,[M,4096]) aliases qkv+bias.

#define B_ 4
#define N_ 512
#define D_ 1024
#define H_ 16
#define HID_ 4096
#define M_ (B_*N_)

typedef unsigned short u16;
typedef __attribute__((ext_vector_type(8))) short bf16x8;
typedef __attribute__((ext_vector_type(4))) float f32x4;

__device__ __forceinline__ float b2f(u16 u){
  union { unsigned int i; float f; } x; x.i = ((unsigned int)u) << 16; return x.f;
}
__device__ __forceinline__ u16 f2b(float f){          // RNE (epilogue quality)
  unsigned int u = __float_as_uint(f);
  return (u16)((u + 0x7fffu + ((u >> 16) & 1u)) >> 16);
}
__device__ __forceinline__ unsigned pk2(float a, float b){   // fast pack lo=a hi=b
  unsigned ua = (__float_as_uint(a) + 0x8000u) >> 16;
  unsigned ub = (__float_as_uint(b) + 0x8000u) & 0xffff0000u;
  return ua | ub;
}

// ---------------- adaLN modulation (f32, tiny)
__global__ __launch_bounds__(256) void k_mod(const float* __restrict__ t_emb,
    const float* __restrict__ w_ada, const float* __restrict__ b_ada,
    float* __restrict__ mod)
{
  __shared__ float st[D_];
  int b = blockIdx.y;
  for (int i = threadIdx.x; i < D_; i += 256){
    float x = t_emb[b*D_ + i];
    st[i] = x / (1.f + __expf(-x));
  }
  __syncthreads();
  int j = blockIdx.x * 256 + threadIdx.x;
  const float* wr = w_ada + (size_t)j * D_;
  float acc = b_ada[j];
  for (int k = 0; k < D_; k += 8){
    float4 p0 = *(const float4*)(wr + k);
    float4 p1 = *(const float4*)(wr + k + 4);
    acc += p0.x*st[k+0] + p0.y*st[k+1] + p0.z*st[k+2] + p0.w*st[k+3];
    acc += p1.x*st[k+4] + p1.y*st[k+5] + p1.z*st[k+6] + p1.w*st[k+7];
  }
  mod[b*6*D_ + j] = acc;
}

// ---------------- LayerNorm + adaLN modulate -> f32
__global__ __launch_bounds__(256) void k_lnmod(const float* __restrict__ xin,
    const float* __restrict__ g, const float* __restrict__ be,
    const float* __restrict__ mod, int shift_idx, int scale_idx,
    float* __restrict__ xn)
{
  int row = blockIdx.x;
  int b = row >> 9;
  float v[4]; float s = 0.f, s2 = 0.f;
  #pragma unroll
  for (int i=0;i<4;i++){
    float x = xin[(size_t)row*D_ + threadIdx.x + i*256];
    v[i] = x; s += x; s2 += x*x;
  }
  #pragma unroll
  for (int o=32;o>0;o>>=1){ s += __shfl_down(s,o); s2 += __shfl_down(s2,o); }
  __shared__ float rs[4], rs2[4];
  int w = threadIdx.x >> 6;
  if ((threadIdx.x & 63)==0){ rs[w]=s; rs2[w]=s2; }
  __syncthreads();
  s = rs[0]+rs[1]+rs[2]+rs[3]; s2 = rs2[0]+rs2[1]+rs2[2]+rs2[3];
  float mu = s * (1.f/D_);
  float var = s2 * (1.f/D_) - mu*mu;
  float rstd = rsqrtf(var + 1e-5f);
  const float* mrow = mod + b*6*D_;
  #pragma unroll
  for (int i=0;i<4;i++){
    int d = threadIdx.x + i*256;
    float xg = (v[i]-mu)*rstd*g[d] + be[d];
    xn[(size_t)row*D_ + d] = xg * (1.f + mrow[scale_idx*D_ + d]) + mrow[shift_idx*D_ + d];
  }
}

// ---------------- rel-pos bias MLP -> bf16 bias[b,h,n,m], mask folded in
__global__ __launch_bounds__(256) void k_bias(const float* __restrict__ rel,
    const int* __restrict__ amask,
    const float* __restrict__ w_rp1, const float* __restrict__ b_rp1,
    const float* __restrict__ w_rp2, const float* __restrict__ b_rp2,
    u16* __restrict__ biasbuf)
{
  __shared__ float w1[128], b1s[64], w2s[H_*64], b2s[H_];
  int tid = threadIdx.x;
  if (tid < 128) w1[tid] = w_rp1[tid];
  if (tid < 64)  b1s[tid] = b_rp1[tid];
  for (int i=tid;i<H_*64;i+=256) w2s[i] = w_rp2[i];
  if (tid < H_)  b2s[tid] = b_rp2[tid];
  __syncthreads();
  int b = blockIdx.z, n = blockIdx.y;
  int m = blockIdx.x*256 + tid;
  float2 r01 = *(const float2*)(rel + ((size_t)((b*N_ + n)*N_) + m)*2);
  float hid[64];
  #pragma unroll
  for (int j=0;j<64;j++){
    float t = w1[2*j]*r01.x + w1[2*j+1]*r01.y + b1s[j];
    hid[j] = t > 0.f ? t : 0.f;
  }
  bool valid = amask[b*N_ + m] != 0;
  size_t base = ((size_t)(b*H_)*N_ + n)*N_ + m;
  for (int h=0; h<H_; h++){
    float acc = b2s[h];
    #pragma unroll
    for (int j=0;j<64;j++) acc += hid[j]*w2s[h*64+j];
    biasbuf[base + (size_t)h*N_*N_] = f2b(valid ? acc : -1e30f);
  }
}

// ---------------- MFMA GEMM: C = A @ W^T + bias, 128x128 tile, BK=32
// A: f32 or bf16 [M,K]; W f32 [NO,K]. Epilogues fused.
enum { EPI_QKV=0, EPI_PROJ=1, EPI_FC1=2, EPI_FC2=3 };

template<int EPI, bool A_BF16>
__global__ __launch_bounds__(256) void k_gemm(const void* __restrict__ Ain,
    const float* __restrict__ W, const float* __restrict__ Wb, int K, int NOUT,
    const float* __restrict__ mod, const float* __restrict__ resid,
    float* __restrict__ o_f32, u16* __restrict__ o_u16)
{
  __shared__ __align__(16) u16 Al[128*40];
  __shared__ __align__(16) u16 Wl[128*40];
  int row0 = blockIdx.y*128, col0 = blockIdx.x*128;
  int tid = threadIdx.x;
  int w = tid >> 6, lane = tid & 63, ln = lane & 15, quad = lane >> 4;
  int wy = w >> 1, wx = w & 1;
  int srow = tid >> 1, scb = (tid & 1) * 16;
  f32x4 acc[4][4] = {};

  for (int k0 = 0; k0 < K; k0 += 32){
    // stage A
    if (A_BF16){
      const u16* src = (const u16*)Ain + (size_t)(row0+srow)*K + k0 + scb;
      uint4 a0 = *(const uint4*)src, a1 = *(const uint4*)(src+8);
      uint4* dst = (uint4*)&Al[srow*40 + scb];
      dst[0] = a0; dst[1] = a1;
    } else {
      const float* src = (const float*)Ain + (size_t)(row0+srow)*K + k0 + scb;
      float4 p0 = *(const float4*)src,     p1 = *(const float4*)(src+4);
      float4 p2 = *(const float4*)(src+8), p3 = *(const float4*)(src+12);
      uint4 d0 = { pk2(p0.x,p0.y), pk2(p0.z,p0.w), pk2(p1.x,p1.y), pk2(p1.z,p1.w) };
      uint4 d1 = { pk2(p2.x,p2.y), pk2(p2.z,p2.w), pk2(p3.x,p3.y), pk2(p3.z,p3.w) };
      uint4* dst = (uint4*)&Al[srow*40 + scb];
      dst[0] = d0; dst[1] = d1;
    }
    // stage W
    {
      const float* src = W + (size_t)(col0+srow)*K + k0 + scb;
      float4 p0 = *(const float4*)src,     p1 = *(const float4*)(src+4);
      float4 p2 = *(const float4*)(src+8), p3 = *(const float4*)(src+12);
      uint4 d0 = { pk2(p0.x,p0.y), pk2(p0.z,p0.w), pk2(p1.x,p1.y), pk2(p1.z,p1.w) };
      uint4 d1 = { pk2(p2.x,p2.y), pk2(p2.z,p2.w), pk2(p3.x,p3.y), pk2(p3.z,p3.w) };
      uint4* dst = (uint4*)&Wl[srow*40 + scb];
      dst[0] = d0; dst[1] = d1;
    }
    __syncthreads();
    bf16x8 af[4], bf_[4];
    #pragma unroll
    for (int ms=0; ms<4; ms++) af[ms] = *(const bf16x8*)&Al[(64*wy+16*ms+ln)*40 + quad*8];
    #pragma unroll
    for (int ns=0; ns<4; ns++) bf_[ns] = *(const bf16x8*)&Wl[(64*wx+16*ns+ln)*40 + quad*8];
    #pragma unroll
    for (int ms=0; ms<4; ms++)
      #pragma unroll
      for (int ns=0; ns<4; ns++)
        acc[ms][ns] = __builtin_amdgcn_mfma_f32_16x16x32_bf16(af[ms], bf_[ns], acc[ms][ns], 0,0,0);
    __syncthreads();
  }

  #pragma unroll
  for (int ms=0; ms<4; ms++){
    #pragma unroll
    for (int ns=0; ns<4; ns++){
      int cbase = col0 + 64*wx + 16*ns + ln;
      float wb = Wb[cbase];
      #pragma unroll
      for (int i=0;i<4;i++){
        int r = row0 + 64*wy + 16*ms + quad*4 + i;
        int c = cbase;
        int b = r >> 9;
        float val = acc[ms][ns][i] + wb;
        if (EPI == EPI_QKV){
          o_u16[(size_t)r*3072 + c] = f2b(val);
        } else if (EPI == EPI_PROJ){
          float gte = mod[b*6*D_ + 2*D_ + c];
          o_f32[(size_t)r*D_ + c] = resid[(size_t)r*D_ + c] + gte * val;
        } else if (EPI == EPI_FC1){
          float gl = 0.5f*val*(1.f + erff(val*0.70710678f));
          o_u16[(size_t)r*HID_ + c] = f2b(gl);
        } else {
          float gte = mod[b*6*D_ + 5*D_ + c];
          o_f32[(size_t)r*D_ + c] = resid[(size_t)r*D_ + c] + gte * val;
        }
      }
    }
  }
}

// ---------------- flash attention: block = (b,h,ntile of 128 rows), 8 waves
__global__ __launch_bounds__(512) void k_attn(const u16* __restrict__ qkv,
    const u16* __restrict__ biasbuf, float* __restrict__ attn_out)
{
  __shared__ __align__(16) u16 Qs[128*72];   // 18432 B
  __shared__ __align__(16) u16 Ks[64*72];    //  9216 B
  __shared__ __align__(16) u16 Vt[64*72];    //  9216 B
  __shared__ __align__(16) u16 Ps[8*16*72];  // 18432 B
  int nt = blockIdx.x, h = blockIdx.y, b = blockIdx.z;
  int n0 = nt*128;
  int tid = threadIdx.x;
  int w = tid >> 6, lane = tid & 63, ln = lane & 15, quad = lane >> 4;

  // stage Q (bf16 copy)
  {
    int row = tid >> 2, cb = (tid & 3)*16;
    const u16* src = qkv + (size_t)(b*N_ + n0 + row)*3072 + h*64 + cb;
    uint4 q0 = *(const uint4*)src, q1 = *(const uint4*)(src+8);
    uint4* dst = (uint4*)&Qs[row*72 + cb];
    dst[0] = q0; dst[1] = q1;
  }
  __syncthreads();
  bf16x8 qf[2];
  qf[0] = *(const bf16x8*)&Qs[(16*w+ln)*72 + quad*8];
  qf[1] = *(const bf16x8*)&Qs[(16*w+ln)*72 + 32 + quad*8];

  f32x4 oacc[4] = {};
  float rmax[4] = {-3e38f,-3e38f,-3e38f,-3e38f};
  float rsum[4] = {0.f,0.f,0.f,0.f};
  const u16* bp = biasbuf + (((size_t)(b*H_ + h)*N_) + n0 + 16*w)*N_ + ln;

  for (int mt = 0; mt < 8; mt++){
    __syncthreads();
    { // stage K and V^T for this m-tile
      int r = tid >> 3, cb = (tid & 7)*8;
      const u16* kp = qkv + (size_t)(b*N_ + mt*64 + r)*3072 + 1024 + h*64 + cb;
      *(uint4*)&Ks[r*72 + cb] = *(const uint4*)kp;
      const u16* vp = qkv + (size_t)(b*N_ + mt*64 + r)*3072 + 2048 + h*64 + cb;
      uint4 vv = *(const uint4*)vp;
      u16 ve[8] = { (u16)(vv.x&0xffff),(u16)(vv.x>>16),(u16)(vv.y&0xffff),(u16)(vv.y>>16),
                    (u16)(vv.z&0xffff),(u16)(vv.z>>16),(u16)(vv.w&0xffff),(u16)(vv.w>>16) };
      #pragma unroll
      for (int j=0;j<8;j++) Vt[(cb+j)*72 + r] = ve[j];
    }
    __syncthreads();

    // bias tile loads (early for latency)
    u16 bl[4][4];
    #pragma unroll
    for (int cs=0; cs<4; cs++)
      #pragma unroll
      for (int i=0;i<4;i++)
        bl[cs][i] = bp[(size_t)(quad*4+i)*N_ + mt*64 + 16*cs];

    // S = Q K^T
    f32x4 s[4];
    #pragma unroll
    for (int cs=0; cs<4; cs++){
      bf16x8 k0f = *(const bf16x8*)&Ks[(16*cs+ln)*72 + quad*8];
      bf16x8 k1f = *(const bf16x8*)&Ks[(16*cs+ln)*72 + 32 + quad*8];
      f32x4 z = {};
      z = __builtin_amdgcn_mfma_f32_16x16x32_bf16(qf[0], k0f, z, 0,0,0);
      z = __builtin_amdgcn_mfma_f32_16x16x32_bf16(qf[1], k1f, z, 0,0,0);
      s[cs] = z;
    }
    // scale + bias(+mask)
    #pragma unroll
    for (int cs=0; cs<4; cs++)
      #pragma unroll
      for (int i=0;i<4;i++)
        s[cs][i] = s[cs][i]*0.125f + b2f(bl[cs][i]);

    // online softmax (rows = quad*4+i, cols spread over 16 lanes x 4 cs)
    #pragma unroll
    for (int i=0;i<4;i++){
      float tm = fmaxf(fmaxf(s[0][i], s[1][i]), fmaxf(s[2][i], s[3][i]));
      #pragma unroll
      for (int o=1;o<16;o<<=1) tm = fmaxf(tm, __shfl_xor(tm, o));
      float nm = fmaxf(rmax[i], tm);
      float alpha = __expf(rmax[i] - nm);
      rmax[i] = nm;
      float ps = 0.f;
      #pragma unroll
      for (int cs=0; cs<4; cs++){
        float p = __expf(s[cs][i] - nm);
        s[cs][i] = p; ps += p;
      }
      #pragma unroll
      for (int o=1;o<16;o<<=1) ps += __shfl_xor(ps, o);
      rsum[i] = rsum[i]*alpha + ps;
      #pragma unroll
      for (int ds=0; ds<4; ds++) oacc[ds][i] *= alpha;
    }

    // P -> LDS (A-layout entry), wave-private
    #pragma unroll
    for (int cs=0; cs<4; cs++)
      #pragma unroll
      for (int i=0;i<4;i++)
        Ps[w*1152 + (quad*4+i)*72 + 16*cs + ln] = f2b(s[cs][i]);

    bf16x8 pf0 = *(const bf16x8*)&Ps[w*1152 + ln*72 + quad*8];
    bf16x8 pf1 = *(const bf16x8*)&Ps[w*1152 + ln*72 + 32 + quad*8];
    #pragma unroll
    for (int ds=0; ds<4; ds++){
      bf16x8 v0f = *(const bf16x8*)&Vt[(16*ds+ln)*72 + quad*8];
      bf16x8 v1f = *(const bf16x8*)&Vt[(16*ds+ln)*72 + 32 + quad*8];
      oacc[ds] = __builtin_amdgcn_mfma_f32_16x16x32_bf16(pf0, v0f, oacc[ds], 0,0,0);
      oacc[ds] = __builtin_amdgcn_mfma_f32_16x16x32_bf16(pf1, v1f, oacc[ds], 0,0,0);
    }
  }

  #pragma unroll
  for (int i=0;i<4;i++){
    float inv = 1.f / rsum[i];
    int r = b*N_ + n0 + 16*w + quad*4 + i;
    #pragma unroll
    for (int ds=0; ds<4; ds++)
      attn_out[(size_t)r*D_ + h*64 + 16*ds + ln] = oacc[ds][i]*inv;
  }
}

extern "C" void kernel_launch(void* const* d_in, const int* in_sizes, int n_in,
                              void* d_out, int out_size, void* d_ws, size_t ws_size,
                              hipStream_t stream) {
  const float* x      = (const float*)d_in[0];
  const float* t_emb  = (const float*)d_in[1];
  const float* rel    = (const float*)d_in[2];
  const int*   amask  = (const int*)d_in[3];
  const float* w_ada  = (const float*)d_in[4];
  const float* b_ada  = (const float*)d_in[5];
  const float* g1     = (const float*)d_in[6];
  const float* beta1  = (const float*)d_in[7];
  const float* g2     = (const float*)d_in[8];
  const float* beta2  = (const float*)d_in[9];
  const float* w_qkv  = (const float*)d_in[10];
  const float* b_qkv  = (const float*)d_in[11];
  const float* w_proj = (const float*)d_in[12];
  const float* b_proj = (const float*)d_in[13];
  const float* w_rp1  = (const float*)d_in[14];
  const float* b_rp1  = (const float*)d_in[15];
  const float* w_rp2  = (const float*)d_in[16];
  const float* b_rp2  = (const float*)d_in[17];
  const float* w_fc1  = (const float*)d_in[18];
  const float* b_fc1  = (const float*)d_in[19];
  const float* w_fc2  = (const float*)d_in[20];
  const float* b_fc2  = (const float*)d_in[21];
  float* outp = (float*)d_out;

  float* ws   = (float*)d_ws;
  float* mod  = ws;                          // 24576
  float* xn   = mod + 6*D_*B_;               // 2097152 (reused: attn_out, xn2)
  float* xm   = xn  + (size_t)M_*D_;         // 2097152
  u16*  qkvb  = (u16*)(xm + (size_t)M_*D_);  // M*3072 u16 = 3145728 f32 slots
  u16*  biasb = qkvb + (size_t)M_*3072;      // 16777216 u16 = 8388608 f32 slots
  u16*  hb    = qkvb;                        // alias (qkv+bias dead by FC1): M*4096 u16

  k_mod<<<dim3(6*D_/256, B_), 256, 0, stream>>>(t_emb, w_ada, b_ada, mod);
  k_bias<<<dim3(N_/256, N_, B_), 256, 0, stream>>>(rel, amask, w_rp1, b_rp1, w_rp2, b_rp2, biasb);
  k_lnmod<<<M_, 256, 0, stream>>>(x, g1, beta1, mod, 0, 1, xn);
  k_gemm<EPI_QKV, false><<<dim3(3072/128, M_/128), 256, 0, stream>>>(
      xn, w_qkv, b_qkv, D_, 3072, nullptr, nullptr, nullptr, qkvb);
  k_attn<<<dim3(4, H_, B_), 512, 0, stream>>>(qkvb, biasb, xn);
  k_gemm<EPI_PROJ, false><<<dim3(D_/128, M_/128), 256, 0, stream>>>(
      xn, w_proj, b_proj, D_, D_, mod, x, xm, nullptr);
  k_lnmod<<<M_, 256, 0, stream>>>(xm, g2, beta2, mod, 3, 4, xn);
  k_gemm<EPI_FC1, false><<<dim3(HID_/128, M_/128), 256, 0, stream>>>(
      xn, w_fc1, b_fc1, D_, HID_, nullptr, nullptr, nullptr, hb);
  k_gemm<EPI_FC2, true><<<dim3(D_/128, M_/128), 256, 0, stream>>>(
      hb, w_fc2, b_fc2, HID_, D_, mod, xm, outp, nullptr);
}

// Round 4
// 445.096 us; speedup vs baseline: 4.3411x; 1.3226x over previous
//
#include <hip/hip_runtime.h>

// DiT block, B=4 N=512 D=1024 H=16 HD=64 HID=4096 RP_HID=64. All f32 I/O.
// R4: all GEMM operands bf16 in ws; global_load_lds staging (m97 pattern);
//     weights pre-converted once; FC2 split-K x4 via f32 atomics.
// ws layout (byte offsets): mod@0 | xn(u16)@128K | xm(f32)@4.125M | wqkvb@12.125M
//  | wprojb@18.125M | accb(f32)@20.125M | S@28.125M:
//    phase A: qkvb [S+0,12M), biasb [S+12M,44M)
//    phase B: hb [S+0,16M), wfc1b [S+16M,24M), wfc2b [S+24M,32M)
//  total = 28.125M + 44M = 72.125 MB.

#define B_ 4
#define N_ 512
#define D_ 1024
#define H_ 16
#define HID_ 4096
#define M_ (B_*N_)

typedef unsigned short u16;
typedef __attribute__((ext_vector_type(8))) short bf16x8;
typedef __attribute__((ext_vector_type(4))) float f32x4;

__device__ __forceinline__ float b2f(u16 u){
  union { unsigned int i; float f; } x; x.i = ((unsigned int)u) << 16; return x.f;
}
__device__ __forceinline__ u16 f2b(float f){          // RNE
  unsigned int u = __float_as_uint(f);
  return (u16)((u + 0x7fffu + ((u >> 16) & 1u)) >> 16);
}

// async global->LDS, 16B per lane (m97 pattern)
__device__ __forceinline__ void gload16(const u16* __restrict__ g, u16* l){
#if defined(__has_builtin) && __has_builtin(__builtin_amdgcn_global_load_lds)
  __builtin_amdgcn_global_load_lds(
      (const __attribute__((address_space(1))) unsigned int*)g,
      (__attribute__((address_space(3))) unsigned int*)l, 16, 0, 0);
#else
  *(uint4*)l = *(const uint4*)g;
#endif
}

// ---------------- f32 -> bf16 convert (weights), 8 elems/thread
__global__ __launch_bounds__(256) void k_cvt(const float* __restrict__ s, u16* __restrict__ d){
  size_t i = ((size_t)blockIdx.x*256 + threadIdx.x)*8;
  float4 a = *(const float4*)(s+i), b = *(const float4*)(s+i+4);
  u16 o[8] = {f2b(a.x),f2b(a.y),f2b(a.z),f2b(a.w),f2b(b.x),f2b(b.y),f2b(b.z),f2b(b.w)};
  *(uint4*)(d+i) = *(const uint4*)o;
}

__global__ __launch_bounds__(256) void k_zero(float* __restrict__ p){
  size_t i = ((size_t)blockIdx.x*256 + threadIdx.x)*4;
  *(float4*)(p+i) = make_float4(0.f,0.f,0.f,0.f);
}

// ---------------- adaLN modulation (f32, tiny)
__global__ __launch_bounds__(256) void k_mod(const float* __restrict__ t_emb,
    const float* __restrict__ w_ada, const float* __restrict__ b_ada,
    float* __restrict__ mod)
{
  __shared__ float st[D_];
  int b = blockIdx.y;
  for (int i = threadIdx.x; i < D_; i += 256){
    float x = t_emb[b*D_ + i];
    st[i] = x / (1.f + __expf(-x));
  }
  __syncthreads();
  int j = blockIdx.x * 256 + threadIdx.x;
  const float* wr = w_ada + (size_t)j * D_;
  float acc = b_ada[j];
  for (int k = 0; k < D_; k += 8){
    float4 p0 = *(const float4*)(wr + k);
    float4 p1 = *(const float4*)(wr + k + 4);
    acc += p0.x*st[k+0] + p0.y*st[k+1] + p0.z*st[k+2] + p0.w*st[k+3];
    acc += p1.x*st[k+4] + p1.y*st[k+5] + p1.z*st[k+6] + p1.w*st[k+7];
  }
  mod[b*6*D_ + j] = acc;
}

// ---------------- LayerNorm + adaLN modulate -> bf16
__global__ __launch_bounds__(256) void k_lnmod(const float* __restrict__ xin,
    const float* __restrict__ g, const float* __restrict__ be,
    const float* __restrict__ mod, int shift_idx, int scale_idx,
    u16* __restrict__ xn)
{
  int row = blockIdx.x;
  int b = row >> 9;
  float v[4]; float s = 0.f, s2 = 0.f;
  #pragma unroll
  for (int i=0;i<4;i++){
    float x = xin[(size_t)row*D_ + threadIdx.x + i*256];
    v[i] = x; s += x; s2 += x*x;
  }
  #pragma unroll
  for (int o=32;o>0;o>>=1){ s += __shfl_down(s,o); s2 += __shfl_down(s2,o); }
  __shared__ float rs[4], rs2[4];
  int w = threadIdx.x >> 6;
  if ((threadIdx.x & 63)==0){ rs[w]=s; rs2[w]=s2; }
  __syncthreads();
  s = rs[0]+rs[1]+rs[2]+rs[3]; s2 = rs2[0]+rs2[1]+rs2[2]+rs2[3];
  float mu = s * (1.f/D_);
  float var = s2 * (1.f/D_) - mu*mu;
  float rstd = rsqrtf(var + 1e-5f);
  const float* mrow = mod + b*6*D_;
  #pragma unroll
  for (int i=0;i<4;i++){
    int d = threadIdx.x + i*256;
    float xg = (v[i]-mu)*rstd*g[d] + be[d];
    xn[(size_t)row*D_ + d] = f2b(xg * (1.f + mrow[scale_idx*D_ + d]) + mrow[shift_idx*D_ + d]);
  }
}

// ---------------- rel-pos bias MLP -> bf16 bias[b,h,n,m], mask folded in
__global__ __launch_bounds__(256) void k_bias(const float* __restrict__ rel,
    const int* __restrict__ amask,
    const float* __restrict__ w_rp1, const float* __restrict__ b_rp1,
    const float* __restrict__ w_rp2, const float* __restrict__ b_rp2,
    u16* __restrict__ biasbuf)
{
  __shared__ float w1[128], b1s[64], w2s[H_*64], b2s[H_];
  int tid = threadIdx.x;
  if (tid < 128) w1[tid] = w_rp1[tid];
  if (tid < 64)  b1s[tid] = b_rp1[tid];
  for (int i=tid;i<H_*64;i+=256) w2s[i] = w_rp2[i];
  if (tid < H_)  b2s[tid] = b_rp2[tid];
  __syncthreads();
  int b = blockIdx.z, n = blockIdx.y;
  int m = blockIdx.x*256 + tid;
  float2 r01 = *(const float2*)(rel + ((size_t)((b*N_ + n)*N_) + m)*2);
  float hid[64];
  #pragma unroll
  for (int j=0;j<64;j++){
    float t = w1[2*j]*r01.x + w1[2*j+1]*r01.y + b1s[j];
    hid[j] = t > 0.f ? t : 0.f;
  }
  bool valid = amask[b*N_ + m] != 0;
  size_t base = ((size_t)(b*H_)*N_ + n)*N_ + m;
  for (int h=0; h<H_; h++){
    float acc = b2s[h];
    #pragma unroll
    for (int j=0;j<64;j++) acc += hid[j]*w2s[h*64+j];
    biasbuf[base + (size_t)h*N_*N_] = f2b(valid ? acc : -1e30f);
  }
}

// ---------------- MFMA GEMM: C = A(bf16)@W(bf16)^T, 128x128 tile, BK=32,
// global_load_lds staging. EPI_ACC: split-K atomic accumulate (no bias).
enum { EPI_QKV=0, EPI_PROJ=1, EPI_FC1=2, EPI_ACC=3 };

template<int EPI>
__global__ __launch_bounds__(256) void k_gemm(const u16* __restrict__ A,
    const u16* __restrict__ W, const float* __restrict__ Wb, int K, int Kslice,
    const float* __restrict__ mod, const float* __restrict__ resid,
    float* __restrict__ o_f32, u16* __restrict__ o_u16, float* __restrict__ accb)
{
  __shared__ __align__(16) u16 Al[128*32];
  __shared__ __align__(16) u16 Wl[128*32];
  int row0 = blockIdx.y*128, col0 = blockIdx.x*128;
  int tid = threadIdx.x;
  int w = tid >> 6, lane = tid & 63, ln = lane & 15, quad = lane >> 4;
  int wy = w >> 1, wx = w & 1;
  int sub = tid & 3, r0 = tid >> 2;
  const u16* Ag = A + (size_t)(row0 + r0)*K + sub*8;
  const u16* Wg = W + (size_t)(col0 + r0)*K + sub*8;
  u16* Al0 = Al + tid*8;  u16* Al1 = Al + 2048 + tid*8;
  u16* Wl0 = Wl + tid*8;  u16* Wl1 = Wl + 2048 + tid*8;
  size_t rshift = (size_t)64*K;
  f32x4 acc[4][4] = {};

  int kbeg = blockIdx.z * Kslice;
  for (int k0 = kbeg; k0 < kbeg + Kslice; k0 += 32){
    gload16(Ag + k0,          Al0);
    gload16(Ag + rshift + k0, Al1);
    gload16(Wg + k0,          Wl0);
    gload16(Wg + rshift + k0, Wl1);
    __syncthreads();
    bf16x8 af[4], bfr[4];
    #pragma unroll
    for (int ms=0; ms<4; ms++) af[ms]  = *(const bf16x8*)&Al[(64*wy+16*ms+ln)*32 + quad*8];
    #pragma unroll
    for (int ns=0; ns<4; ns++) bfr[ns] = *(const bf16x8*)&Wl[(64*wx+16*ns+ln)*32 + quad*8];
    #pragma unroll
    for (int ms=0; ms<4; ms++)
      #pragma unroll
      for (int ns=0; ns<4; ns++)
        acc[ms][ns] = __builtin_amdgcn_mfma_f32_16x16x32_bf16(af[ms], bfr[ns], acc[ms][ns], 0,0,0);
    __syncthreads();
  }

  #pragma unroll
  for (int ms=0; ms<4; ms++){
    #pragma unroll
    for (int ns=0; ns<4; ns++){
      int c = col0 + 64*wx + 16*ns + ln;
      float wb = (EPI == EPI_ACC) ? 0.f : Wb[c];
      #pragma unroll
      for (int i=0;i<4;i++){
        int r = row0 + 64*wy + 16*ms + quad*4 + i;
        int b = r >> 9;
        float val = acc[ms][ns][i] + wb;
        if (EPI == EPI_QKV){
          o_u16[(size_t)r*3072 + c] = f2b(val);
        } else if (EPI == EPI_PROJ){
          float gte = mod[b*6*D_ + 2*D_ + c];
          o_f32[(size_t)r*D_ + c] = resid[(size_t)r*D_ + c] + gte * val;
        } else if (EPI == EPI_FC1){
          float gl = 0.5f*val*(1.f + erff(val*0.70710678f));
          o_u16[(size_t)r*HID_ + c] = f2b(gl);
        } else {
          atomicAdd(&accb[(size_t)r*D_ + c], val);
        }
      }
    }
  }
}

// ---------------- FC2 reduce epilogue: out = xm + gate_m*(acc + bias)
__global__ __launch_bounds__(256) void k_fc2red(const float* __restrict__ accb,
    const float* __restrict__ Wb, const float* __restrict__ mod,
    const float* __restrict__ xm, float* __restrict__ outp)
{
  size_t i = ((size_t)blockIdx.x*256 + threadIdx.x)*4;
  int r = (int)(i >> 10), c = (int)(i & 1023), b = r >> 9;
  float4 a = *(const float4*)(accb + i);
  float4 x4 = *(const float4*)(xm + i);
  float4 bi = *(const float4*)(Wb + c);
  float4 g4 = *(const float4*)(mod + b*6*D_ + 5*D_ + c);
  float4 o;
  o.x = x4.x + g4.x*(a.x + bi.x);
  o.y = x4.y + g4.y*(a.y + bi.y);
  o.z = x4.z + g4.z*(a.z + bi.z);
  o.w = x4.w + g4.w*(a.w + bi.w);
  *(float4*)(outp + i) = o;
}

// ---------------- flash attention: block = (nt, h, b), 8 waves; bf16 out
__global__ __launch_bounds__(512) void k_attn(const u16* __restrict__ qkv,
    const u16* __restrict__ biasbuf, u16* __restrict__ attn_out)
{
  __shared__ __align__(16) u16 Qs[128*72];
  __shared__ __align__(16) u16 Ks[64*72];
  __shared__ __align__(16) u16 Vt[64*72];
  __shared__ __align__(16) u16 Ps[8*16*72];
  int nt = blockIdx.x, h = blockIdx.y, b = blockIdx.z;
  int n0 = nt*128;
  int tid = threadIdx.x;
  int w = tid >> 6, lane = tid & 63, ln = lane & 15, quad = lane >> 4;

  {
    int row = tid >> 2, cb = (tid & 3)*16;
    const u16* src = qkv + (size_t)(b*N_ + n0 + row)*3072 + h*64 + cb;
    uint4 q0 = *(const uint4*)src, q1 = *(const uint4*)(src+8);
    uint4* dst = (uint4*)&Qs[row*72 + cb];
    dst[0] = q0; dst[1] = q1;
  }
  __syncthreads();
  bf16x8 qf[2];
  qf[0] = *(const bf16x8*)&Qs[(16*w+ln)*72 + quad*8];
  qf[1] = *(const bf16x8*)&Qs[(16*w+ln)*72 + 32 + quad*8];

  f32x4 oacc[4] = {};
  float rmax[4] = {-3e38f,-3e38f,-3e38f,-3e38f};
  float rsum[4] = {0.f,0.f,0.f,0.f};
  const u16* bp = biasbuf + (((size_t)(b*H_ + h)*N_) + n0 + 16*w)*N_ + ln;

  for (int mt = 0; mt < 8; mt++){
    __syncthreads();
    {
      int r = tid >> 3, cb = (tid & 7)*8;
      const u16* kp = qkv + (size_t)(b*N_ + mt*64 + r)*3072 + 1024 + h*64 + cb;
      *(uint4*)&Ks[r*72 + cb] = *(const uint4*)kp;
      const u16* vp = qkv + (size_t)(b*N_ + mt*64 + r)*3072 + 2048 + h*64 + cb;
      uint4 vv = *(const uint4*)vp;
      u16 ve[8] = { (u16)(vv.x&0xffff),(u16)(vv.x>>16),(u16)(vv.y&0xffff),(u16)(vv.y>>16),
                    (u16)(vv.z&0xffff),(u16)(vv.z>>16),(u16)(vv.w&0xffff),(u16)(vv.w>>16) };
      #pragma unroll
      for (int j=0;j<8;j++) Vt[(cb+j)*72 + r] = ve[j];
    }
    __syncthreads();

    u16 bl[4][4];
    #pragma unroll
    for (int cs=0; cs<4; cs++)
      #pragma unroll
      for (int i=0;i<4;i++)
        bl[cs][i] = bp[(size_t)(quad*4+i)*N_ + mt*64 + 16*cs];

    f32x4 s[4];
    #pragma unroll
    for (int cs=0; cs<4; cs++){
      bf16x8 k0f = *(const bf16x8*)&Ks[(16*cs+ln)*72 + quad*8];
      bf16x8 k1f = *(const bf16x8*)&Ks[(16*cs+ln)*72 + 32 + quad*8];
      f32x4 z = {};
      z = __builtin_amdgcn_mfma_f32_16x16x32_bf16(qf[0], k0f, z, 0,0,0);
      z = __builtin_amdgcn_mfma_f32_16x16x32_bf16(qf[1], k1f, z, 0,0,0);
      s[cs] = z;
    }
    #pragma unroll
    for (int cs=0; cs<4; cs++)
      #pragma unroll
      for (int i=0;i<4;i++)
        s[cs][i] = s[cs][i]*0.125f + b2f(bl[cs][i]);

    #pragma unroll
    for (int i=0;i<4;i++){
      float tm = fmaxf(fmaxf(s[0][i], s[1][i]), fmaxf(s[2][i], s[3][i]));
      #pragma unroll
      for (int o=1;o<16;o<<=1) tm = fmaxf(tm, __shfl_xor(tm, o));
      float nm = fmaxf(rmax[i], tm);
      float alpha = __expf(rmax[i] - nm);
      rmax[i] = nm;
      float ps = 0.f;
      #pragma unroll
      for (int cs=0; cs<4; cs++){
        float p = __expf(s[cs][i] - nm);
        s[cs][i] = p; ps += p;
      }
      #pragma unroll
      for (int o=1;o<16;o<<=1) ps += __shfl_xor(ps, o);
      rsum[i] = rsum[i]*alpha + ps;
      #pragma unroll
      for (int ds=0; ds<4; ds++) oacc[ds][i] *= alpha;
    }

    #pragma unroll
    for (int cs=0; cs<4; cs++)
      #pragma unroll
      for (int i=0;i<4;i++)
        Ps[w*1152 + (quad*4+i)*72 + 16*cs + ln] = f2b(s[cs][i]);

    bf16x8 pf0 = *(const bf16x8*)&Ps[w*1152 + ln*72 + quad*8];
    bf16x8 pf1 = *(const bf16x8*)&Ps[w*1152 + ln*72 + 32 + quad*8];
    #pragma unroll
    for (int ds=0; ds<4; ds++){
      bf16x8 v0f = *(const bf16x8*)&Vt[(16*ds+ln)*72 + quad*8];
      bf16x8 v1f = *(const bf16x8*)&Vt[(16*ds+ln)*72 + 32 + quad*8];
      oacc[ds] = __builtin_amdgcn_mfma_f32_16x16x32_bf16(pf0, v0f, oacc[ds], 0,0,0);
      oacc[ds] = __builtin_amdgcn_mfma_f32_16x16x32_bf16(pf1, v1f, oacc[ds], 0,0,0);
    }
  }

  #pragma unroll
  for (int i=0;i<4;i++){
    float inv = 1.f / rsum[i];
    int r = b*N_ + n0 + 16*w + quad*4 + i;
    #pragma unroll
    for (int ds=0; ds<4; ds++)
      attn_out[(size_t)r*D_ + h*64 + 16*ds + ln] = f2b(oacc[ds][i]*inv);
  }
}

extern "C" void kernel_launch(void* const* d_in, const int* in_sizes, int n_in,
                              void* d_out, int out_size, void* d_ws, size_t ws_size,
                              hipStream_t stream) {
  const float* x      = (const float*)d_in[0];
  const float* t_emb  = (const float*)d_in[1];
  const float* rel    = (const float*)d_in[2];
  const int*   amask  = (const int*)d_in[3];
  const float* w_ada  = (const float*)d_in[4];
  const float* b_ada  = (const float*)d_in[5];
  const float* g1     = (const float*)d_in[6];
  const float* beta1  = (const float*)d_in[7];
  const float* g2     = (const float*)d_in[8];
  const float* beta2  = (const float*)d_in[9];
  const float* w_qkv  = (const float*)d_in[10];
  const float* b_qkv  = (const float*)d_in[11];
  const float* w_proj = (const float*)d_in[12];
  const float* b_proj = (const float*)d_in[13];
  const float* w_rp1  = (const float*)d_in[14];
  const float* b_rp1  = (const float*)d_in[15];
  const float* w_rp2  = (const float*)d_in[16];
  const float* b_rp2  = (const float*)d_in[17];
  const float* w_fc1  = (const float*)d_in[18];
  const float* b_fc1  = (const float*)d_in[19];
  const float* w_fc2  = (const float*)d_in[20];
  const float* b_fc2  = (const float*)d_in[21];
  float* outp = (float*)d_out;

  const size_t MB = 1u<<20;
  char* wsb = (char*)d_ws;
  float* mod   = (float*)(wsb);                       // 24576 f32
  u16*  xn     = (u16*) (wsb + 131072);               // [M,1024] u16 (ln out / attn out)
  float* xm    = (float*)(wsb + 131072 + 4*MB);       // [M,1024] f32
  u16*  wqkvb  = (u16*) (wsb + 131072 + 12*MB);       // [3072,1024]
  u16*  wprojb = (u16*) (wsb + 131072 + 18*MB);       // [1024,1024]
  float* accb  = (float*)(wsb + 131072 + 20*MB);      // [M,1024] f32 (FC2 acc)
  char*  S     = wsb + 131072 + 28*MB;
  u16*  qkvb   = (u16*)(S);                           // [M,3072]
  u16*  biasb  = (u16*)(S + 12*MB);                   // [B,H,N,N]
  u16*  hb     = (u16*)(S);                           // [M,4096] (phase B)
  u16*  wfc1b  = (u16*)(S + 16*MB);                   // [4096,1024]
  u16*  wfc2b  = (u16*)(S + 24*MB);                   // [1024,4096]

  // weight converts (qkv/proj up front; fc1/fc2 after attention frees S regions)
  k_cvt<<<1536, 256, 0, stream>>>(w_qkv,  wqkvb);
  k_cvt<<<512,  256, 0, stream>>>(w_proj, wprojb);
  k_mod<<<dim3(6*D_/256, B_), 256, 0, stream>>>(t_emb, w_ada, b_ada, mod);
  k_bias<<<dim3(N_/256, N_, B_), 256, 0, stream>>>(rel, amask, w_rp1, b_rp1, w_rp2, b_rp2, biasb);
  k_lnmod<<<M_, 256, 0, stream>>>(x, g1, beta1, mod, 0, 1, xn);
  k_gemm<EPI_QKV><<<dim3(3072/128, M_/128), 256, 0, stream>>>(
      xn, wqkvb, b_qkv, D_, D_, nullptr, nullptr, nullptr, qkvb, nullptr);
  k_attn<<<dim3(4, H_, B_), 512, 0, stream>>>(qkvb, biasb, xn);
  k_cvt<<<2048, 256, 0, stream>>>(w_fc1, wfc1b);
  k_cvt<<<2048, 256, 0, stream>>>(w_fc2, wfc2b);
  k_gemm<EPI_PROJ><<<dim3(D_/128, M_/128), 256, 0, stream>>>(
      xn, wprojb, b_proj, D_, D_, mod, x, xm, nullptr, nullptr);
  k_lnmod<<<M_, 256, 0, stream>>>(xm, g2, beta2, mod, 3, 4, xn);
  k_gemm<EPI_FC1><<<dim3(HID_/128, M_/128), 256, 0, stream>>>(
      xn, wfc1b, b_fc1, D_, D_, nullptr, nullptr, nullptr, hb, nullptr);
  k_zero<<<2048, 256, 0, stream>>>(accb);
  k_gemm<EPI_ACC><<<dim3(D_/128, M_/128, 4), 256, 0, stream>>>(
      hb, wfc2b, nullptr, HID_, HID_/4, nullptr, nullptr, nullptr, nullptr, accb);
  k_fc2red<<<2048, 256, 0, stream>>>(accb, b_fc2, mod, xm, outp);
}

// Round 5
// 411.681 us; speedup vs baseline: 4.6935x; 1.0812x over previous
//
#include <hip/hip_runtime.h>

// DiT block, B=4 N=512 D=1024 H=16 HD=64 HID=4096 RP_HID=64. All f32 I/O.
// R5: k_bias rewritten -> MFMA second layer + coalesced writes.
// ws layout (byte offsets): mod@0 | xn(u16)@128K | xm(f32)@4.125M | wqkvb@12.125M
//  | wprojb@18.125M | accb(f32)@20.125M | S@28.125M:
//    phase A: qkvb [S+0,12M), biasb [S+12M,44M)
//    phase B: hb [S+0,16M), wfc1b [S+16M,24M), wfc2b [S+24M,32M)
//  total = 28.125M + 44M = 72.125 MB.

#define B_ 4
#define N_ 512
#define D_ 1024
#define H_ 16
#define HID_ 4096
#define M_ (B_*N_)

typedef unsigned short u16;
typedef __attribute__((ext_vector_type(8))) short bf16x8;
typedef __attribute__((ext_vector_type(4))) float f32x4;

__device__ __forceinline__ float b2f(u16 u){
  union { unsigned int i; float f; } x; x.i = ((unsigned int)u) << 16; return x.f;
}
__device__ __forceinline__ u16 f2b(float f){          // RNE
  unsigned int u = __float_as_uint(f);
  return (u16)((u + 0x7fffu + ((u >> 16) & 1u)) >> 16);
}

// async global->LDS, 16B per lane (m97 pattern)
__device__ __forceinline__ void gload16(const u16* __restrict__ g, u16* l){
#if defined(__has_builtin) && __has_builtin(__builtin_amdgcn_global_load_lds)
  __builtin_amdgcn_global_load_lds(
      (const __attribute__((address_space(1))) unsigned int*)g,
      (__attribute__((address_space(3))) unsigned int*)l, 16, 0, 0);
#else
  *(uint4*)l = *(const uint4*)g;
#endif
}

// ---------------- f32 -> bf16 convert (weights), 8 elems/thread
__global__ __launch_bounds__(256) void k_cvt(const float* __restrict__ s, u16* __restrict__ d){
  size_t i = ((size_t)blockIdx.x*256 + threadIdx.x)*8;
  float4 a = *(const float4*)(s+i), b = *(const float4*)(s+i+4);
  u16 o[8] = {f2b(a.x),f2b(a.y),f2b(a.z),f2b(a.w),f2b(b.x),f2b(b.y),f2b(b.z),f2b(b.w)};
  *(uint4*)(d+i) = *(const uint4*)o;
}

__global__ __launch_bounds__(256) void k_zero(float* __restrict__ p){
  size_t i = ((size_t)blockIdx.x*256 + threadIdx.x)*4;
  *(float4*)(p+i) = make_float4(0.f,0.f,0.f,0.f);
}

// ---------------- adaLN modulation (f32, tiny)
__global__ __launch_bounds__(256) void k_mod(const float* __restrict__ t_emb,
    const float* __restrict__ w_ada, const float* __restrict__ b_ada,
    float* __restrict__ mod)
{
  __shared__ float st[D_];
  int b = blockIdx.y;
  for (int i = threadIdx.x; i < D_; i += 256){
    float x = t_emb[b*D_ + i];
    st[i] = x / (1.f + __expf(-x));
  }
  __syncthreads();
  int j = blockIdx.x * 256 + threadIdx.x;
  const float* wr = w_ada + (size_t)j * D_;
  float acc = b_ada[j];
  for (int k = 0; k < D_; k += 8){
    float4 p0 = *(const float4*)(wr + k);
    float4 p1 = *(const float4*)(wr + k + 4);
    acc += p0.x*st[k+0] + p0.y*st[k+1] + p0.z*st[k+2] + p0.w*st[k+3];
    acc += p1.x*st[k+4] + p1.y*st[k+5] + p1.z*st[k+6] + p1.w*st[k+7];
  }
  mod[b*6*D_ + j] = acc;
}

// ---------------- LayerNorm + adaLN modulate -> bf16
__global__ __launch_bounds__(256) void k_lnmod(const float* __restrict__ xin,
    const float* __restrict__ g, const float* __restrict__ be,
    const float* __restrict__ mod, int shift_idx, int scale_idx,
    u16* __restrict__ xn)
{
  int row = blockIdx.x;
  int b = row >> 9;
  float v[4]; float s = 0.f, s2 = 0.f;
  #pragma unroll
  for (int i=0;i<4;i++){
    float x = xin[(size_t)row*D_ + threadIdx.x + i*256];
    v[i] = x; s += x; s2 += x*x;
  }
  #pragma unroll
  for (int o=32;o>0;o>>=1){ s += __shfl_down(s,o); s2 += __shfl_down(s2,o); }
  __shared__ float rs[4], rs2[4];
  int w = threadIdx.x >> 6;
  if ((threadIdx.x & 63)==0){ rs[w]=s; rs2[w]=s2; }
  __syncthreads();
  s = rs[0]+rs[1]+rs[2]+rs[3]; s2 = rs2[0]+rs2[1]+rs2[2]+rs2[3];
  float mu = s * (1.f/D_);
  float var = s2 * (1.f/D_) - mu*mu;
  float rstd = rsqrtf(var + 1e-5f);
  const float* mrow = mod + b*6*D_;
  #pragma unroll
  for (int i=0;i<4;i++){
    int d = threadIdx.x + i*256;
    float xg = (v[i]-mu)*rstd*g[d] + be[d];
    xn[(size_t)row*D_ + d] = f2b(xg * (1.f + mrow[scale_idx*D_ + d]) + mrow[shift_idx*D_ + d]);
  }
}

// ---------------- rel-pos bias MLP -> bf16 bias[b,h,n,m], mask folded in.
// Block = (mh, n, b): 256 m-columns, all 16 heads. Layer-2 via MFMA.
__global__ __launch_bounds__(256) void k_bias(const float* __restrict__ rel,
    const int* __restrict__ amask,
    const float* __restrict__ w_rp1, const float* __restrict__ b_rp1,
    const float* __restrict__ w_rp2, const float* __restrict__ b_rp2,
    u16* __restrict__ biasbuf)
{
  __shared__ __align__(16) u16 Hs[256*72];   // hid bf16, stride 72
  __shared__ __align__(16) u16 Bs[16*272];   // staged output rows
  __shared__ __align__(16) u16 w2s[16*72];   // w_rp2 bf16, stride 72
  __shared__ float b2s[16];
  __shared__ u16 msk[256];
  int mh = blockIdx.x, n = blockIdx.y, b = blockIdx.z;
  int tid = threadIdx.x;
  int w = tid >> 6, lane = tid & 63, ln = lane & 15, quad = lane >> 4;

  // stage w_rp2 (bf16), b2, mask
  for (int i = tid; i < 1024; i += 256) w2s[(i>>6)*72 + (i&63)] = f2b(w_rp2[i]);
  if (tid < 16) b2s[tid] = b_rp2[tid];
  msk[tid] = (u16)(amask[b*N_ + mh*256 + tid] != 0);

  // hid for m = mh*256 + tid
  {
    float2 r01 = *(const float2*)(rel + ((size_t)((b*N_ + n)*N_) + mh*256 + tid)*2);
    const float* w1 = w_rp1;
    u16 hv[64];
    #pragma unroll
    for (int j=0;j<64;j++){
      float t = w1[2*j]*r01.x + w1[2*j+1]*r01.y + b_rp1[j];
      hv[j] = f2b(t > 0.f ? t : 0.f);
    }
    uint4* dst = (uint4*)&Hs[tid*72];
    #pragma unroll
    for (int c=0;c<8;c++) dst[c] = *(const uint4*)&hv[c*8];
  }
  __syncthreads();

  // A-frag: w_rp2 rows (h), loaded once per wave
  bf16x8 af0 = *(const bf16x8*)&w2s[ln*72 + quad*8];
  bf16x8 af1 = *(const bf16x8*)&w2s[ln*72 + 32 + quad*8];

  // 4 m-tiles per wave
  #pragma unroll
  for (int t=0; t<4; t++){
    int mt = w*4 + t;                  // tile of 16 m
    bf16x8 bf0 = *(const bf16x8*)&Hs[(mt*16+ln)*72 + quad*8];
    bf16x8 bf1 = *(const bf16x8*)&Hs[(mt*16+ln)*72 + 32 + quad*8];
    f32x4 c = {};
    c = __builtin_amdgcn_mfma_f32_16x16x32_bf16(af0, bf0, c, 0,0,0);
    c = __builtin_amdgcn_mfma_f32_16x16x32_bf16(af1, bf1, c, 0,0,0);
    bool valid = msk[mt*16 + ln] != 0;
    #pragma unroll
    for (int i=0;i<4;i++){
      int h = quad*4 + i;
      float val = valid ? (c[i] + b2s[h]) : -1e30f;
      Bs[h*272 + mt*16 + ln] = f2b(val);
    }
  }
  __syncthreads();

  // coalesced write-out: 16 rows x 512B
  #pragma unroll
  for (int it=0; it<8; it++){
    int idx = it*256 + tid;            // 0..2047
    int r = idx >> 7, cc = idx & 127;
    size_t rb = (((size_t)(b*H_ + r)*N_) + n)*N_ + mh*256;
    ((unsigned int*)(biasbuf + rb))[cc] = ((const unsigned int*)(Bs + r*272))[cc];
  }
}

// ---------------- MFMA GEMM: C = A(bf16)@W(bf16)^T, 128x128 tile, BK=32,
// global_load_lds staging. EPI_ACC: split-K atomic accumulate (no bias).
enum { EPI_QKV=0, EPI_PROJ=1, EPI_FC1=2, EPI_ACC=3 };

template<int EPI>
__global__ __launch_bounds__(256) void k_gemm(const u16* __restrict__ A,
    const u16* __restrict__ W, const float* __restrict__ Wb, int K, int Kslice,
    const float* __restrict__ mod, const float* __restrict__ resid,
    float* __restrict__ o_f32, u16* __restrict__ o_u16, float* __restrict__ accb)
{
  __shared__ __align__(16) u16 Al[128*32];
  __shared__ __align__(16) u16 Wl[128*32];
  int row0 = blockIdx.y*128, col0 = blockIdx.x*128;
  int tid = threadIdx.x;
  int w = tid >> 6, lane = tid & 63, ln = lane & 15, quad = lane >> 4;
  int wy = w >> 1, wx = w & 1;
  int sub = tid & 3, r0 = tid >> 2;
  const u16* Ag = A + (size_t)(row0 + r0)*K + sub*8;
  const u16* Wg = W + (size_t)(col0 + r0)*K + sub*8;
  u16* Al0 = Al + tid*8;  u16* Al1 = Al + 2048 + tid*8;
  u16* Wl0 = Wl + tid*8;  u16* Wl1 = Wl + 2048 + tid*8;
  size_t rshift = (size_t)64*K;
  f32x4 acc[4][4] = {};

  int kbeg = blockIdx.z * Kslice;
  for (int k0 = kbeg; k0 < kbeg + Kslice; k0 += 32){
    gload16(Ag + k0,          Al0);
    gload16(Ag + rshift + k0, Al1);
    gload16(Wg + k0,          Wl0);
    gload16(Wg + rshift + k0, Wl1);
    __syncthreads();
    bf16x8 af[4], bfr[4];
    #pragma unroll
    for (int ms=0; ms<4; ms++) af[ms]  = *(const bf16x8*)&Al[(64*wy+16*ms+ln)*32 + quad*8];
    #pragma unroll
    for (int ns=0; ns<4; ns++) bfr[ns] = *(const bf16x8*)&Wl[(64*wx+16*ns+ln)*32 + quad*8];
    #pragma unroll
    for (int ms=0; ms<4; ms++)
      #pragma unroll
      for (int ns=0; ns<4; ns++)
        acc[ms][ns] = __builtin_amdgcn_mfma_f32_16x16x32_bf16(af[ms], bfr[ns], acc[ms][ns], 0,0,0);
    __syncthreads();
  }

  #pragma unroll
  for (int ms=0; ms<4; ms++){
    #pragma unroll
    for (int ns=0; ns<4; ns++){
      int c = col0 + 64*wx + 16*ns + ln;
      float wb = (EPI == EPI_ACC) ? 0.f : Wb[c];
      #pragma unroll
      for (int i=0;i<4;i++){
        int r = row0 + 64*wy + 16*ms + quad*4 + i;
        int b = r >> 9;
        float val = acc[ms][ns][i] + wb;
        if (EPI == EPI_QKV){
          o_u16[(size_t)r*3072 + c] = f2b(val);
        } else if (EPI == EPI_PROJ){
          float gte = mod[b*6*D_ + 2*D_ + c];
          o_f32[(size_t)r*D_ + c] = resid[(size_t)r*D_ + c] + gte * val;
        } else if (EPI == EPI_FC1){
          float gl = 0.5f*val*(1.f + erff(val*0.70710678f));
          o_u16[(size_t)r*HID_ + c] = f2b(gl);
        } else {
          atomicAdd(&accb[(size_t)r*D_ + c], val);
        }
      }
    }
  }
}

// ---------------- FC2 reduce epilogue: out = xm + gate_m*(acc + bias)
__global__ __launch_bounds__(256) void k_fc2red(const float* __restrict__ accb,
    const float* __restrict__ Wb, const float* __restrict__ mod,
    const float* __restrict__ xm, float* __restrict__ outp)
{
  size_t i = ((size_t)blockIdx.x*256 + threadIdx.x)*4;
  int r = (int)(i >> 10), c = (int)(i & 1023), b = r >> 9;
  float4 a = *(const float4*)(accb + i);
  float4 x4 = *(const float4*)(xm + i);
  float4 bi = *(const float4*)(Wb + c);
  float4 g4 = *(const float4*)(mod + b*6*D_ + 5*D_ + c);
  float4 o;
  o.x = x4.x + g4.x*(a.x + bi.x);
  o.y = x4.y + g4.y*(a.y + bi.y);
  o.z = x4.z + g4.z*(a.z + bi.z);
  o.w = x4.w + g4.w*(a.w + bi.w);
  *(float4*)(outp + i) = o;
}

// ---------------- flash attention: block = (nt, h, b), 8 waves; bf16 out
__global__ __launch_bounds__(512) void k_attn(const u16* __restrict__ qkv,
    const u16* __restrict__ biasbuf, u16* __restrict__ attn_out)
{
  __shared__ __align__(16) u16 Qs[128*72];
  __shared__ __align__(16) u16 Ks[64*72];
  __shared__ __align__(16) u16 Vt[64*72];
  __shared__ __align__(16) u16 Ps[8*16*72];
  int nt = blockIdx.x, h = blockIdx.y, b = blockIdx.z;
  int n0 = nt*128;
  int tid = threadIdx.x;
  int w = tid >> 6, lane = tid & 63, ln = lane & 15, quad = lane >> 4;

  {
    int row = tid >> 2, cb = (tid & 3)*16;
    const u16* src = qkv + (size_t)(b*N_ + n0 + row)*3072 + h*64 + cb;
    uint4 q0 = *(const uint4*)src, q1 = *(const uint4*)(src+8);
    uint4* dst = (uint4*)&Qs[row*72 + cb];
    dst[0] = q0; dst[1] = q1;
  }
  __syncthreads();
  bf16x8 qf[2];
  qf[0] = *(const bf16x8*)&Qs[(16*w+ln)*72 + quad*8];
  qf[1] = *(const bf16x8*)&Qs[(16*w+ln)*72 + 32 + quad*8];

  f32x4 oacc[4] = {};
  float rmax[4] = {-3e38f,-3e38f,-3e38f,-3e38f};
  float rsum[4] = {0.f,0.f,0.f,0.f};
  const u16* bp = biasbuf + (((size_t)(b*H_ + h)*N_) + n0 + 16*w)*N_ + ln;

  for (int mt = 0; mt < 8; mt++){
    __syncthreads();
    {
      int r = tid >> 3, cb = (tid & 7)*8;
      const u16* kp = qkv + (size_t)(b*N_ + mt*64 + r)*3072 + 1024 + h*64 + cb;
      *(uint4*)&Ks[r*72 + cb] = *(const uint4*)kp;
      const u16* vp = qkv + (size_t)(b*N_ + mt*64 + r)*3072 + 2048 + h*64 + cb;
      uint4 vv = *(const uint4*)vp;
      u16 ve[8] = { (u16)(vv.x&0xffff),(u16)(vv.x>>16),(u16)(vv.y&0xffff),(u16)(vv.y>>16),
                    (u16)(vv.z&0xffff),(u16)(vv.z>>16),(u16)(vv.w&0xffff),(u16)(vv.w>>16) };
      #pragma unroll
      for (int j=0;j<8;j++) Vt[(cb+j)*72 + r] = ve[j];
    }
    __syncthreads();

    u16 bl[4][4];
    #pragma unroll
    for (int cs=0; cs<4; cs++)
      #pragma unroll
      for (int i=0;i<4;i++)
        bl[cs][i] = bp[(size_t)(quad*4+i)*N_ + mt*64 + 16*cs];

    f32x4 s[4];
    #pragma unroll
    for (int cs=0; cs<4; cs++){
      bf16x8 k0f = *(const bf16x8*)&Ks[(16*cs+ln)*72 + quad*8];
      bf16x8 k1f = *(const bf16x8*)&Ks[(16*cs+ln)*72 + 32 + quad*8];
      f32x4 z = {};
      z = __builtin_amdgcn_mfma_f32_16x16x32_bf16(qf[0], k0f, z, 0,0,0);
      z = __builtin_amdgcn_mfma_f32_16x16x32_bf16(qf[1], k1f, z, 0,0,0);
      s[cs] = z;
    }
    #pragma unroll
    for (int cs=0; cs<4; cs++)
      #pragma unroll
      for (int i=0;i<4;i++)
        s[cs][i] = s[cs][i]*0.125f + b2f(bl[cs][i]);

    #pragma unroll
    for (int i=0;i<4;i++){
      float tm = fmaxf(fmaxf(s[0][i], s[1][i]), fmaxf(s[2][i], s[3][i]));
      #pragma unroll
      for (int o=1;o<16;o<<=1) tm = fmaxf(tm, __shfl_xor(tm, o));
      float nm = fmaxf(rmax[i], tm);
      float alpha = __expf(rmax[i] - nm);
      rmax[i] = nm;
      float ps = 0.f;
      #pragma unroll
      for (int cs=0; cs<4; cs++){
        float p = __expf(s[cs][i] - nm);
        s[cs][i] = p; ps += p;
      }
      #pragma unroll
      for (int o=1;o<16;o<<=1) ps += __shfl_xor(ps, o);
      rsum[i] = rsum[i]*alpha + ps;
      #pragma unroll
      for (int ds=0; ds<4; ds++) oacc[ds][i] *= alpha;
    }

    #pragma unroll
    for (int cs=0; cs<4; cs++)
      #pragma unroll
      for (int i=0;i<4;i++)
        Ps[w*1152 + (quad*4+i)*72 + 16*cs + ln] = f2b(s[cs][i]);

    bf16x8 pf0 = *(const bf16x8*)&Ps[w*1152 + ln*72 + quad*8];
    bf16x8 pf1 = *(const bf16x8*)&Ps[w*1152 + ln*72 + 32 + quad*8];
    #pragma unroll
    for (int ds=0; ds<4; ds++){
      bf16x8 v0f = *(const bf16x8*)&Vt[(16*ds+ln)*72 + quad*8];
      bf16x8 v1f = *(const bf16x8*)&Vt[(16*ds+ln)*72 + 32 + quad*8];
      oacc[ds] = __builtin_amdgcn_mfma_f32_16x16x32_bf16(pf0, v0f, oacc[ds], 0,0,0);
      oacc[ds] = __builtin_amdgcn_mfma_f32_16x16x32_bf16(pf1, v1f, oacc[ds], 0,0,0);
    }
  }

  #pragma unroll
  for (int i=0;i<4;i++){
    float inv = 1.f / rsum[i];
    int r = b*N_ + n0 + 16*w + quad*4 + i;
    #pragma unroll
    for (int ds=0; ds<4; ds++)
      attn_out[(size_t)r*D_ + h*64 + 16*ds + ln] = f2b(oacc[ds][i]*inv);
  }
}

extern "C" void kernel_launch(void* const* d_in, const int* in_sizes, int n_in,
                              void* d_out, int out_size, void* d_ws, size_t ws_size,
                              hipStream_t stream) {
  const float* x      = (const float*)d_in[0];
  const float* t_emb  = (const float*)d_in[1];
  const float* rel    = (const float*)d_in[2];
  const int*   amask  = (const int*)d_in[3];
  const float* w_ada  = (const float*)d_in[4];
  const float* b_ada  = (const float*)d_in[5];
  const float* g1     = (const float*)d_in[6];
  const float* beta1  = (const float*)d_in[7];
  const float* g2     = (const float*)d_in[8];
  const float* beta2  = (const float*)d_in[9];
  const float* w_qkv  = (const float*)d_in[10];
  const float* b_qkv  = (const float*)d_in[11];
  const float* w_proj = (const float*)d_in[12];
  const float* b_proj = (const float*)d_in[13];
  const float* w_rp1  = (const float*)d_in[14];
  const float* b_rp1  = (const float*)d_in[15];
  const float* w_rp2  = (const float*)d_in[16];
  const float* b_rp2  = (const float*)d_in[17];
  const float* w_fc1  = (const float*)d_in[18];
  const float* b_fc1  = (const float*)d_in[19];
  const float* w_fc2  = (const float*)d_in[20];
  const float* b_fc2  = (const float*)d_in[21];
  float* outp = (float*)d_out;

  const size_t MB = 1u<<20;
  char* wsb = (char*)d_ws;
  float* mod   = (float*)(wsb);                       // 24576 f32
  u16*  xn     = (u16*) (wsb + 131072);               // [M,1024] u16 (ln out / attn out)
  float* xm    = (float*)(wsb + 131072 + 4*MB);       // [M,1024] f32
  u16*  wqkvb  = (u16*) (wsb + 131072 + 12*MB);       // [3072,1024]
  u16*  wprojb = (u16*) (wsb + 131072 + 18*MB);       // [1024,1024]
  float* accb  = (float*)(wsb + 131072 + 20*MB);      // [M,1024] f32 (FC2 acc)
  char*  S     = wsb + 131072 + 28*MB;
  u16*  qkvb   = (u16*)(S);                           // [M,3072]
  u16*  biasb  = (u16*)(S + 12*MB);                   // [B,H,N,N]
  u16*  hb     = (u16*)(S);                           // [M,4096] (phase B)
  u16*  wfc1b  = (u16*)(S + 16*MB);                   // [4096,1024]
  u16*  wfc2b  = (u16*)(S + 24*MB);                   // [1024,4096]

  k_cvt<<<1536, 256, 0, stream>>>(w_qkv,  wqkvb);
  k_cvt<<<512,  256, 0, stream>>>(w_proj, wprojb);
  k_mod<<<dim3(6*D_/256, B_), 256, 0, stream>>>(t_emb, w_ada, b_ada, mod);
  k_bias<<<dim3(2, N_, B_), 256, 0, stream>>>(rel, amask, w_rp1, b_rp1, w_rp2, b_rp2, biasb);
  k_lnmod<<<M_, 256, 0, stream>>>(x, g1, beta1, mod, 0, 1, xn);
  k_gemm<EPI_QKV><<<dim3(3072/128, M_/128), 256, 0, stream>>>(
      xn, wqkvb, b_qkv, D_, D_, nullptr, nullptr, nullptr, qkvb, nullptr);
  k_attn<<<dim3(4, H_, B_), 512, 0, stream>>>(qkvb, biasb, xn);
  k_cvt<<<2048, 256, 0, stream>>>(w_fc1, wfc1b);
  k_cvt<<<2048, 256, 0, stream>>>(w_fc2, wfc2b);
  k_gemm<EPI_PROJ><<<dim3(D_/128, M_/128), 256, 0, stream>>>(
      xn, wprojb, b_proj, D_, D_, mod, x, xm, nullptr, nullptr);
  k_lnmod<<<M_, 256, 0, stream>>>(xm, g2, beta2, mod, 3, 4, xn);
  k_gemm<EPI_FC1><<<dim3(HID_/128, M_/128), 256, 0, stream>>>(
      xn, wfc1b, b_fc1, D_, D_, nullptr, nullptr, nullptr, hb, nullptr);
  k_zero<<<2048, 256, 0, stream>>>(accb);
  k_gemm<EPI_ACC><<<dim3(D_/128, M_/128, 4), 256, 0, stream>>>(
      hb, wfc2b, nullptr, HID_, HID_/4, nullptr, nullptr, nullptr, nullptr, accb);
  k_fc2red<<<2048, 256, 0, stream>>>(accb, b_fc2, mod, xm, outp);
}

// Round 6
// 373.909 us; speedup vs baseline: 5.1676x; 1.1010x over previous
//
#include <hip/hip_runtime.h>

// DiT block, B=4 N=512 D=1024 H=16 HD=64 HID=4096 RP_HID=64. All f32 I/O.
// R6: BK=64 + XOR-swizzled LDS (kills 8-way bank conflicts); FC2/PROJ via
//     non-atomic split-K x2 bf16 partials + fused reduce.
// ws layout (byte offsets): mod@0 | xn(u16)@128K | xm(f32)@4.125M | wqkvb@12.125M
//  | wprojb@18.125M | partb(u16 2x[M,1024])@20.125M | S@28.125M:
//    phase A: qkvb [S+0,12M), biasb [S+12M,44M)
//    phase B: hb [S+0,16M), wfc1b [S+16M,24M), wfc2b [S+24M,32M)

#define B_ 4
#define N_ 512
#define D_ 1024
#define H_ 16
#define HID_ 4096
#define M_ (B_*N_)

typedef unsigned short u16;
typedef __attribute__((ext_vector_type(8))) short bf16x8;
typedef __attribute__((ext_vector_type(4))) float f32x4;

__device__ __forceinline__ float b2f(u16 u){
  union { unsigned int i; float f; } x; x.i = ((unsigned int)u) << 16; return x.f;
}
__device__ __forceinline__ u16 f2b(float f){          // RNE
  unsigned int u = __float_as_uint(f);
  return (u16)((u + 0x7fffu + ((u >> 16) & 1u)) >> 16);
}

// async global->LDS, 16B per lane (m97 pattern)
__device__ __forceinline__ void gload16(const u16* __restrict__ g, u16* l){
#if defined(__has_builtin) && __has_builtin(__builtin_amdgcn_global_load_lds)
  __builtin_amdgcn_global_load_lds(
      (const __attribute__((address_space(1))) unsigned int*)g,
      (__attribute__((address_space(3))) unsigned int*)l, 16, 0, 0);
#else
  *(uint4*)l = *(const uint4*)g;
#endif
}

// ---------------- f32 -> bf16 convert (weights), 8 elems/thread
__global__ __launch_bounds__(256) void k_cvt(const float* __restrict__ s, u16* __restrict__ d){
  size_t i = ((size_t)blockIdx.x*256 + threadIdx.x)*8;
  float4 a = *(const float4*)(s+i), b = *(const float4*)(s+i+4);
  u16 o[8] = {f2b(a.x),f2b(a.y),f2b(a.z),f2b(a.w),f2b(b.x),f2b(b.y),f2b(b.z),f2b(b.w)};
  *(uint4*)(d+i) = *(const uint4*)o;
}

// ---------------- adaLN modulation (f32, tiny)
__global__ __launch_bounds__(256) void k_mod(const float* __restrict__ t_emb,
    const float* __restrict__ w_ada, const float* __restrict__ b_ada,
    float* __restrict__ mod)
{
  __shared__ float st[D_];
  int b = blockIdx.y;
  for (int i = threadIdx.x; i < D_; i += 256){
    float x = t_emb[b*D_ + i];
    st[i] = x / (1.f + __expf(-x));
  }
  __syncthreads();
  int j = blockIdx.x * 256 + threadIdx.x;
  const float* wr = w_ada + (size_t)j * D_;
  float acc = b_ada[j];
  for (int k = 0; k < D_; k += 8){
    float4 p0 = *(const float4*)(wr + k);
    float4 p1 = *(const float4*)(wr + k + 4);
    acc += p0.x*st[k+0] + p0.y*st[k+1] + p0.z*st[k+2] + p0.w*st[k+3];
    acc += p1.x*st[k+4] + p1.y*st[k+5] + p1.z*st[k+6] + p1.w*st[k+7];
  }
  mod[b*6*D_ + j] = acc;
}

// ---------------- LayerNorm + adaLN modulate -> bf16
__global__ __launch_bounds__(256) void k_lnmod(const float* __restrict__ xin,
    const float* __restrict__ g, const float* __restrict__ be,
    const float* __restrict__ mod, int shift_idx, int scale_idx,
    u16* __restrict__ xn)
{
  int row = blockIdx.x;
  int b = row >> 9;
  float v[4]; float s = 0.f, s2 = 0.f;
  #pragma unroll
  for (int i=0;i<4;i++){
    float x = xin[(size_t)row*D_ + threadIdx.x + i*256];
    v[i] = x; s += x; s2 += x*x;
  }
  #pragma unroll
  for (int o=32;o>0;o>>=1){ s += __shfl_down(s,o); s2 += __shfl_down(s2,o); }
  __shared__ float rs[4], rs2[4];
  int w = threadIdx.x >> 6;
  if ((threadIdx.x & 63)==0){ rs[w]=s; rs2[w]=s2; }
  __syncthreads();
  s = rs[0]+rs[1]+rs[2]+rs[3]; s2 = rs2[0]+rs2[1]+rs2[2]+rs2[3];
  float mu = s * (1.f/D_);
  float var = s2 * (1.f/D_) - mu*mu;
  float rstd = rsqrtf(var + 1e-5f);
  const float* mrow = mod + b*6*D_;
  #pragma unroll
  for (int i=0;i<4;i++){
    int d = threadIdx.x + i*256;
    float xg = (v[i]-mu)*rstd*g[d] + be[d];
    xn[(size_t)row*D_ + d] = f2b(xg * (1.f + mrow[scale_idx*D_ + d]) + mrow[shift_idx*D_ + d]);
  }
}

// ---------------- rel-pos bias MLP -> bf16 bias[b,h,n,m], mask folded in.
__global__ __launch_bounds__(256) void k_bias(const float* __restrict__ rel,
    const int* __restrict__ amask,
    const float* __restrict__ w_rp1, const float* __restrict__ b_rp1,
    const float* __restrict__ w_rp2, const float* __restrict__ b_rp2,
    u16* __restrict__ biasbuf)
{
  __shared__ __align__(16) u16 Hs[256*72];
  __shared__ __align__(16) u16 Bs[16*272];
  __shared__ __align__(16) u16 w2s[16*72];
  __shared__ float b2s[16];
  __shared__ u16 msk[256];
  int mh = blockIdx.x, n = blockIdx.y, b = blockIdx.z;
  int tid = threadIdx.x;
  int w = tid >> 6, lane = tid & 63, ln = lane & 15, quad = lane >> 4;

  for (int i = tid; i < 1024; i += 256) w2s[(i>>6)*72 + (i&63)] = f2b(w_rp2[i]);
  if (tid < 16) b2s[tid] = b_rp2[tid];
  msk[tid] = (u16)(amask[b*N_ + mh*256 + tid] != 0);

  {
    float2 r01 = *(const float2*)(rel + ((size_t)((b*N_ + n)*N_) + mh*256 + tid)*2);
    const float* w1 = w_rp1;
    u16 hv[64];
    #pragma unroll
    for (int j=0;j<64;j++){
      float t = w1[2*j]*r01.x + w1[2*j+1]*r01.y + b_rp1[j];
      hv[j] = f2b(t > 0.f ? t : 0.f);
    }
    uint4* dst = (uint4*)&Hs[tid*72];
    #pragma unroll
    for (int c=0;c<8;c++) dst[c] = *(const uint4*)&hv[c*8];
  }
  __syncthreads();

  bf16x8 af0 = *(const bf16x8*)&w2s[ln*72 + quad*8];
  bf16x8 af1 = *(const bf16x8*)&w2s[ln*72 + 32 + quad*8];

  #pragma unroll
  for (int t=0; t<4; t++){
    int mt = w*4 + t;
    bf16x8 bf0 = *(const bf16x8*)&Hs[(mt*16+ln)*72 + quad*8];
    bf16x8 bf1 = *(const bf16x8*)&Hs[(mt*16+ln)*72 + 32 + quad*8];
    f32x4 c = {};
    c = __builtin_amdgcn_mfma_f32_16x16x32_bf16(af0, bf0, c, 0,0,0);
    c = __builtin_amdgcn_mfma_f32_16x16x32_bf16(af1, bf1, c, 0,0,0);
    bool valid = msk[mt*16 + ln] != 0;
    #pragma unroll
    for (int i=0;i<4;i++){
      int h = quad*4 + i;
      float val = valid ? (c[i] + b2s[h]) : -1e30f;
      Bs[h*272 + mt*16 + ln] = f2b(val);
    }
  }
  __syncthreads();

  #pragma unroll
  for (int it=0; it<8; it++){
    int idx = it*256 + tid;
    int r = idx >> 7, cc = idx & 127;
    size_t rb = (((size_t)(b*H_ + r)*N_) + n)*N_ + mh*256;
    ((unsigned int*)(biasbuf + rb))[cc] = ((const unsigned int*)(Bs + r*272))[cc];
  }
}

// ---------------- MFMA GEMM: C = A(bf16)@W(bf16)^T, 128x128 tile, BK=64,
// XOR-swizzled LDS (conflict-free frag reads), global_load_lds staging.
enum { EPI_QKV=0, EPI_FC1=1, EPI_PART=2 };

template<int EPI>
__global__ __launch_bounds__(256) void k_gemm(const u16* __restrict__ A,
    const u16* __restrict__ W, const float* __restrict__ Wb, int K, int Kslice,
    float* __restrict__ o_f32, u16* __restrict__ o_u16)
{
  __shared__ __align__(16) u16 Al[128*64];   // 16 KB
  __shared__ __align__(16) u16 Wl[128*64];   // 16 KB
  int row0 = blockIdx.y*128, col0 = blockIdx.x*128;
  int tid = threadIdx.x;
  int w = tid >> 6, lane = tid & 63, ln = lane & 15, quad = lane >> 4;
  int wy = w >> 1, wx = w & 1;
  int srow = tid >> 3;                       // 0..31
  int schunk = (tid & 7) ^ (srow & 7);       // swizzled global chunk for this lane
  const u16* Ag = A + (size_t)(row0 + srow)*K + schunk*8;
  const u16* Wg = W + (size_t)(col0 + srow)*K + schunk*8;
  // fragment LDS offsets (u16 units), precomputed; row&7 == ln&7
  int aoff[4][2], woff[4][2];
  #pragma unroll
  for (int ms=0; ms<4; ms++){
    int r = 64*wy + 16*ms + ln;
    #pragma unroll
    for (int kk=0; kk<2; kk++)
      aoff[ms][kk] = r*64 + (((kk*4+quad) ^ (ln&7))*8);
  }
  #pragma unroll
  for (int ns=0; ns<4; ns++){
    int r = 64*wx + 16*ns + ln;
    #pragma unroll
    for (int kk=0; kk<2; kk++)
      woff[ns][kk] = r*64 + (((kk*4+quad) ^ (ln&7))*8);
  }
  f32x4 acc[4][4] = {};
  int kbeg = blockIdx.z * Kslice;
  for (int k0 = kbeg; k0 < kbeg + Kslice; k0 += 64){
    #pragma unroll
    for (int i=0;i<4;i++){
      gload16(Ag + k0 + (size_t)(32*i)*K, Al + i*2048 + tid*8);
      gload16(Wg + k0 + (size_t)(32*i)*K, Wl + i*2048 + tid*8);
    }
    __syncthreads();
    #pragma unroll
    for (int kk=0; kk<2; kk++){
      bf16x8 af[4], bfr[4];
      #pragma unroll
      for (int ms=0; ms<4; ms++) af[ms]  = *(const bf16x8*)&Al[aoff[ms][kk]];
      #pragma unroll
      for (int ns=0; ns<4; ns++) bfr[ns] = *(const bf16x8*)&Wl[woff[ns][kk]];
      #pragma unroll
      for (int ms=0; ms<4; ms++)
        #pragma unroll
        for (int ns=0; ns<4; ns++)
          acc[ms][ns] = __builtin_amdgcn_mfma_f32_16x16x32_bf16(af[ms], bfr[ns], acc[ms][ns], 0,0,0);
    }
    __syncthreads();
  }

  #pragma unroll
  for (int ms=0; ms<4; ms++){
    #pragma unroll
    for (int ns=0; ns<4; ns++){
      int c = col0 + 64*wx + 16*ns + ln;
      float wb = (EPI == EPI_PART) ? 0.f : Wb[c];
      #pragma unroll
      for (int i=0;i<4;i++){
        int r = row0 + 64*wy + 16*ms + quad*4 + i;
        float val = acc[ms][ns][i] + wb;
        if (EPI == EPI_QKV){
          o_u16[(size_t)r*3072 + c] = f2b(val);
        } else if (EPI == EPI_FC1){
          float gl = 0.5f*val*(1.f + erff(val*0.70710678f));
          o_u16[(size_t)r*HID_ + c] = f2b(gl);
        } else {
          o_u16[((size_t)blockIdx.z*M_ + r)*D_ + c] = f2b(val);
        }
      }
    }
  }
}

// ---------------- split-K reduce + bias + gate + residual (PROJ: GIDX=2, FC2: GIDX=5)
template<int GIDX>
__global__ __launch_bounds__(256) void k_red(const u16* __restrict__ part,
    const float* __restrict__ Wb, const float* __restrict__ mod,
    const float* __restrict__ resid, float* __restrict__ outp)
{
  size_t i = ((size_t)blockIdx.x*256 + threadIdx.x)*4;
  int c = (int)(i & 1023); int r = (int)(i >> 10); int b = r >> 9;
  uint2 p0 = *(const uint2*)(part + i);
  uint2 p1 = *(const uint2*)(part + (size_t)M_*D_ + i);
  float4 pv;
  pv.x = b2f((u16)(p0.x & 0xffff)) + b2f((u16)(p1.x & 0xffff));
  pv.y = b2f((u16)(p0.x >> 16))    + b2f((u16)(p1.x >> 16));
  pv.z = b2f((u16)(p0.y & 0xffff)) + b2f((u16)(p1.y & 0xffff));
  pv.w = b2f((u16)(p0.y >> 16))    + b2f((u16)(p1.y >> 16));
  float4 x4 = *(const float4*)(resid + i);
  float4 bi = *(const float4*)(Wb + c);
  float4 g4 = *(const float4*)(mod + b*6*D_ + GIDX*D_ + c);
  float4 o;
  o.x = x4.x + g4.x*(pv.x + bi.x);
  o.y = x4.y + g4.y*(pv.y + bi.y);
  o.z = x4.z + g4.z*(pv.z + bi.z);
  o.w = x4.w + g4.w*(pv.w + bi.w);
  *(float4*)(outp + i) = o;
}

// ---------------- flash attention: block = (nt, h, b), 8 waves; bf16 out
__global__ __launch_bounds__(512) void k_attn(const u16* __restrict__ qkv,
    const u16* __restrict__ biasbuf, u16* __restrict__ attn_out)
{
  __shared__ __align__(16) u16 Qs[128*72];
  __shared__ __align__(16) u16 Ks[64*72];
  __shared__ __align__(16) u16 Vt[64*72];
  __shared__ __align__(16) u16 Ps[8*16*72];
  int nt = blockIdx.x, h = blockIdx.y, b = blockIdx.z;
  int n0 = nt*128;
  int tid = threadIdx.x;
  int w = tid >> 6, lane = tid & 63, ln = lane & 15, quad = lane >> 4;

  {
    int row = tid >> 2, cb = (tid & 3)*16;
    const u16* src = qkv + (size_t)(b*N_ + n0 + row)*3072 + h*64 + cb;
    uint4 q0 = *(const uint4*)src, q1 = *(const uint4*)(src+8);
    uint4* dst = (uint4*)&Qs[row*72 + cb];
    dst[0] = q0; dst[1] = q1;
  }
  __syncthreads();
  bf16x8 qf[2];
  qf[0] = *(const bf16x8*)&Qs[(16*w+ln)*72 + quad*8];
  qf[1] = *(const bf16x8*)&Qs[(16*w+ln)*72 + 32 + quad*8];

  f32x4 oacc[4] = {};
  float rmax[4] = {-3e38f,-3e38f,-3e38f,-3e38f};
  float rsum[4] = {0.f,0.f,0.f,0.f};
  const u16* bp = biasbuf + (((size_t)(b*H_ + h)*N_) + n0 + 16*w)*N_ + ln;

  for (int mt = 0; mt < 8; mt++){
    __syncthreads();
    {
      int r = tid >> 3, cb = (tid & 7)*8;
      const u16* kp = qkv + (size_t)(b*N_ + mt*64 + r)*3072 + 1024 + h*64 + cb;
      *(uint4*)&Ks[r*72 + cb] = *(const uint4*)kp;
      const u16* vp = qkv + (size_t)(b*N_ + mt*64 + r)*3072 + 2048 + h*64 + cb;
      uint4 vv = *(const uint4*)vp;
      u16 ve[8] = { (u16)(vv.x&0xffff),(u16)(vv.x>>16),(u16)(vv.y&0xffff),(u16)(vv.y>>16),
                    (u16)(vv.z&0xffff),(u16)(vv.z>>16),(u16)(vv.w&0xffff),(u16)(vv.w>>16) };
      #pragma unroll
      for (int j=0;j<8;j++) Vt[(cb+j)*72 + r] = ve[j];
    }
    __syncthreads();

    u16 bl[4][4];
    #pragma unroll
    for (int cs=0; cs<4; cs++)
      #pragma unroll
      for (int i=0;i<4;i++)
        bl[cs][i] = bp[(size_t)(quad*4+i)*N_ + mt*64 + 16*cs];

    f32x4 s[4];
    #pragma unroll
    for (int cs=0; cs<4; cs++){
      bf16x8 k0f = *(const bf16x8*)&Ks[(16*cs+ln)*72 + quad*8];
      bf16x8 k1f = *(const bf16x8*)&Ks[(16*cs+ln)*72 + 32 + quad*8];
      f32x4 z = {};
      z = __builtin_amdgcn_mfma_f32_16x16x32_bf16(qf[0], k0f, z, 0,0,0);
      z = __builtin_amdgcn_mfma_f32_16x16x32_bf16(qf[1], k1f, z, 0,0,0);
      s[cs] = z;
    }
    #pragma unroll
    for (int cs=0; cs<4; cs++)
      #pragma unroll
      for (int i=0;i<4;i++)
        s[cs][i] = s[cs][i]*0.125f + b2f(bl[cs][i]);

    #pragma unroll
    for (int i=0;i<4;i++){
      float tm = fmaxf(fmaxf(s[0][i], s[1][i]), fmaxf(s[2][i], s[3][i]));
      #pragma unroll
      for (int o=1;o<16;o<<=1) tm = fmaxf(tm, __shfl_xor(tm, o));
      float nm = fmaxf(rmax[i], tm);
      float alpha = __expf(rmax[i] - nm);
      rmax[i] = nm;
      float ps = 0.f;
      #pragma unroll
      for (int cs=0; cs<4; cs++){
        float p = __expf(s[cs][i] - nm);
        s[cs][i] = p; ps += p;
      }
      #pragma unroll
      for (int o=1;o<16;o<<=1) ps += __shfl_xor(ps, o);
      rsum[i] = rsum[i]*alpha + ps;
      #pragma unroll
      for (int ds=0; ds<4; ds++) oacc[ds][i] *= alpha;
    }

    #pragma unroll
    for (int cs=0; cs<4; cs++)
      #pragma unroll
      for (int i=0;i<4;i++)
        Ps[w*1152 + (quad*4+i)*72 + 16*cs + ln] = f2b(s[cs][i]);

    bf16x8 pf0 = *(const bf16x8*)&Ps[w*1152 + ln*72 + quad*8];
    bf16x8 pf1 = *(const bf16x8*)&Ps[w*1152 + ln*72 + 32 + quad*8];
    #pragma unroll
    for (int ds=0; ds<4; ds++){
      bf16x8 v0f = *(const bf16x8*)&Vt[(16*ds+ln)*72 + quad*8];
      bf16x8 v1f = *(const bf16x8*)&Vt[(16*ds+ln)*72 + 32 + quad*8];
      oacc[ds] = __builtin_amdgcn_mfma_f32_16x16x32_bf16(pf0, v0f, oacc[ds], 0,0,0);
      oacc[ds] = __builtin_amdgcn_mfma_f32_16x16x32_bf16(pf1, v1f, oacc[ds], 0,0,0);
    }
  }

  #pragma unroll
  for (int i=0;i<4;i++){
    float inv = 1.f / rsum[i];
    int r = b*N_ + n0 + 16*w + quad*4 + i;
    #pragma unroll
    for (int ds=0; ds<4; ds++)
      attn_out[(size_t)r*D_ + h*64 + 16*ds + ln] = f2b(oacc[ds][i]*inv);
  }
}

extern "C" void kernel_launch(void* const* d_in, const int* in_sizes, int n_in,
                              void* d_out, int out_size, void* d_ws, size_t ws_size,
                              hipStream_t stream) {
  const float* x      = (const float*)d_in[0];
  const float* t_emb  = (const float*)d_in[1];
  const float* rel    = (const float*)d_in[2];
  const int*   amask  = (const int*)d_in[3];
  const float* w_ada  = (const float*)d_in[4];
  const float* b_ada  = (const float*)d_in[5];
  const float* g1     = (const float*)d_in[6];
  const float* beta1  = (const float*)d_in[7];
  const float* g2     = (const float*)d_in[8];
  const float* beta2  = (const float*)d_in[9];
  const float* w_qkv  = (const float*)d_in[10];
  const float* b_qkv  = (const float*)d_in[11];
  const float* w_proj = (const float*)d_in[12];
  const float* b_proj = (const float*)d_in[13];
  const float* w_rp1  = (const float*)d_in[14];
  const float* b_rp1  = (const float*)d_in[15];
  const float* w_rp2  = (const float*)d_in[16];
  const float* b_rp2  = (const float*)d_in[17];
  const float* w_fc1  = (const float*)d_in[18];
  const float* b_fc1  = (const float*)d_in[19];
  const float* w_fc2  = (const float*)d_in[20];
  const float* b_fc2  = (const float*)d_in[21];
  float* outp = (float*)d_out;

  const size_t MB = 1u<<20;
  char* wsb = (char*)d_ws;
  float* mod   = (float*)(wsb);                       // 24576 f32
  u16*  xn     = (u16*) (wsb + 131072);               // [M,1024] u16
  float* xm    = (float*)(wsb + 131072 + 4*MB);       // [M,1024] f32
  u16*  wqkvb  = (u16*) (wsb + 131072 + 12*MB);       // [3072,1024]
  u16*  wprojb = (u16*) (wsb + 131072 + 18*MB);       // [1024,1024]
  u16*  partb  = (u16*) (wsb + 131072 + 20*MB);       // 2 x [M,1024] bf16 partials
  char*  S     = wsb + 131072 + 28*MB;
  u16*  qkvb   = (u16*)(S);                           // [M,3072]
  u16*  biasb  = (u16*)(S + 12*MB);                   // [B,H,N,N]
  u16*  hb     = (u16*)(S);                           // [M,4096] (phase B)
  u16*  wfc1b  = (u16*)(S + 16*MB);                   // [4096,1024]
  u16*  wfc2b  = (u16*)(S + 24*MB);                   // [1024,4096]

  k_cvt<<<1536, 256, 0, stream>>>(w_qkv,  wqkvb);
  k_cvt<<<512,  256, 0, stream>>>(w_proj, wprojb);
  k_mod<<<dim3(6*D_/256, B_), 256, 0, stream>>>(t_emb, w_ada, b_ada, mod);
  k_bias<<<dim3(2, N_, B_), 256, 0, stream>>>(rel, amask, w_rp1, b_rp1, w_rp2, b_rp2, biasb);
  k_lnmod<<<M_, 256, 0, stream>>>(x, g1, beta1, mod, 0, 1, xn);
  k_gemm<EPI_QKV><<<dim3(3072/128, M_/128), 256, 0, stream>>>(
      xn, wqkvb, b_qkv, D_, D_, nullptr, qkvb);
  k_attn<<<dim3(4, H_, B_), 512, 0, stream>>>(qkvb, biasb, xn);
  k_cvt<<<2048, 256, 0, stream>>>(w_fc1, wfc1b);
  k_cvt<<<2048, 256, 0, stream>>>(w_fc2, wfc2b);
  // PROJ: split-K x2 -> bf16 partials -> reduce (gate_s, resid=x) -> xm
  k_gemm<EPI_PART><<<dim3(D_/128, M_/128, 2), 256, 0, stream>>>(
      xn, wprojb, nullptr, D_, D_/2, nullptr, partb);
  k_red<2><<<2048, 256, 0, stream>>>(partb, b_proj, mod, x, xm);
  k_lnmod<<<M_, 256, 0, stream>>>(xm, g2, beta2, mod, 3, 4, xn);
  k_gemm<EPI_FC1><<<dim3(HID_/128, M_/128), 256, 0, stream>>>(
      xn, wfc1b, b_fc1, D_, D_, nullptr, hb);
  // FC2: split-K x2 -> bf16 partials -> reduce (gate_m, resid=xm) -> out
  k_gemm<EPI_PART><<<dim3(D_/128, M_/128, 2), 256, 0, stream>>>(
      hb, wfc2b, nullptr, HID_, HID_/2, nullptr, partb);
  k_red<5><<<2048, 256, 0, stream>>>(partb, b_fc2, mod, xm, outp);
}

// Round 7
// 369.514 us; speedup vs baseline: 5.2291x; 1.0119x over previous
//
#include <hip/hip_runtime.h>

// DiT block, B=4 N=512 D=1024 H=16 HD=64 HID=4096 RP_HID=64. All f32 I/O.
// R7: >=2 blocks/CU everywhere. QKV split-Kx2, PROJ/FC2 split-Kx4 (bf16
//     partials, non-atomic), attention 64-row tiles (512 blocks).
// ws (byte off): mod@0 | xn@128K | xm@128K+4M | wqkvb@+12M | wprojb@+18M |
//   partb@+20M (8M) | S@+28M (44M):
//     QKV partials @S+12M (24M) -> then biasb @S+12M (32M)
//     qkvb @S+0 (12M); PROJ partials 2,3 @S+0 (8M, qkvb dead)
//     hb @S+0 (16M) | wfc1b @S+16M | wfc2b @S+24M | FC2 partials 2,3 @S+32M
// total 72.125 MB (unchanged).

#define B_ 4
#define N_ 512
#define D_ 1024
#define H_ 16
#define HID_ 4096
#define M_ (B_*N_)

typedef unsigned short u16;
typedef __attribute__((ext_vector_type(8))) short bf16x8;
typedef __attribute__((ext_vector_type(4))) float f32x4;

__device__ __forceinline__ float b2f(u16 u){
  union { unsigned int i; float f; } x; x.i = ((unsigned int)u) << 16; return x.f;
}
__device__ __forceinline__ u16 f2b(float f){          // RNE
  unsigned int u = __float_as_uint(f);
  return (u16)((u + 0x7fffu + ((u >> 16) & 1u)) >> 16);
}

__device__ __forceinline__ void gload16(const u16* __restrict__ g, u16* l){
#if defined(__has_builtin) && __has_builtin(__builtin_amdgcn_global_load_lds)
  __builtin_amdgcn_global_load_lds(
      (const __attribute__((address_space(1))) unsigned int*)g,
      (__attribute__((address_space(3))) unsigned int*)l, 16, 0, 0);
#else
  *(uint4*)l = *(const uint4*)g;
#endif
}

// ---------------- f32 -> bf16 convert, two tensors in one launch
__global__ __launch_bounds__(256) void k_cvt2(const float* __restrict__ sA, u16* __restrict__ dA,
    int nA, const float* __restrict__ sB, u16* __restrict__ dB){
  int blk = blockIdx.x;
  const float* s; u16* d; size_t i;
  if (blk < nA){ s = sA; d = dA; i = ((size_t)blk*256 + threadIdx.x)*8; }
  else { s = sB; d = dB; i = ((size_t)(blk-nA)*256 + threadIdx.x)*8; }
  float4 a = *(const float4*)(s+i), b = *(const float4*)(s+i+4);
  u16 o[8] = {f2b(a.x),f2b(a.y),f2b(a.z),f2b(a.w),f2b(b.x),f2b(b.y),f2b(b.z),f2b(b.w)};
  *(uint4*)(d+i) = *(const uint4*)o;
}

// ---------------- adaLN modulation
__global__ __launch_bounds__(256) void k_mod(const float* __restrict__ t_emb,
    const float* __restrict__ w_ada, const float* __restrict__ b_ada,
    float* __restrict__ mod)
{
  __shared__ float st[D_];
  int b = blockIdx.y;
  for (int i = threadIdx.x; i < D_; i += 256){
    float x = t_emb[b*D_ + i];
    st[i] = x / (1.f + __expf(-x));
  }
  __syncthreads();
  int j = blockIdx.x * 256 + threadIdx.x;
  const float* wr = w_ada + (size_t)j * D_;
  float acc = b_ada[j];
  for (int k = 0; k < D_; k += 8){
    float4 p0 = *(const float4*)(wr + k);
    float4 p1 = *(const float4*)(wr + k + 4);
    acc += p0.x*st[k+0] + p0.y*st[k+1] + p0.z*st[k+2] + p0.w*st[k+3];
    acc += p1.x*st[k+4] + p1.y*st[k+5] + p1.z*st[k+6] + p1.w*st[k+7];
  }
  mod[b*6*D_ + j] = acc;
}

// ---------------- LayerNorm + adaLN modulate -> bf16
__global__ __launch_bounds__(256) void k_lnmod(const float* __restrict__ xin,
    const float* __restrict__ g, const float* __restrict__ be,
    const float* __restrict__ mod, int shift_idx, int scale_idx,
    u16* __restrict__ xn)
{
  int row = blockIdx.x;
  int b = row >> 9;
  float v[4]; float s = 0.f, s2 = 0.f;
  #pragma unroll
  for (int i=0;i<4;i++){
    float x = xin[(size_t)row*D_ + threadIdx.x + i*256];
    v[i] = x; s += x; s2 += x*x;
  }
  #pragma unroll
  for (int o=32;o>0;o>>=1){ s += __shfl_down(s,o); s2 += __shfl_down(s2,o); }
  __shared__ float rs[4], rs2[4];
  int w = threadIdx.x >> 6;
  if ((threadIdx.x & 63)==0){ rs[w]=s; rs2[w]=s2; }
  __syncthreads();
  s = rs[0]+rs[1]+rs[2]+rs[3]; s2 = rs2[0]+rs2[1]+rs2[2]+rs2[3];
  float mu = s * (1.f/D_);
  float var = s2 * (1.f/D_) - mu*mu;
  float rstd = rsqrtf(var + 1e-5f);
  const float* mrow = mod + b*6*D_;
  #pragma unroll
  for (int i=0;i<4;i++){
    int d = threadIdx.x + i*256;
    float xg = (v[i]-mu)*rstd*g[d] + be[d];
    xn[(size_t)row*D_ + d] = f2b(xg * (1.f + mrow[scale_idx*D_ + d]) + mrow[shift_idx*D_ + d]);
  }
}

// ---------------- rel-pos bias MLP -> bf16 bias[b,h,n,m]
__global__ __launch_bounds__(256) void k_bias(const float* __restrict__ rel,
    const int* __restrict__ amask,
    const float* __restrict__ w_rp1, const float* __restrict__ b_rp1,
    const float* __restrict__ w_rp2, const float* __restrict__ b_rp2,
    u16* __restrict__ biasbuf)
{
  __shared__ __align__(16) u16 Hs[256*72];
  __shared__ __align__(16) u16 Bs[16*272];
  __shared__ __align__(16) u16 w2s[16*72];
  __shared__ float b2s[16];
  __shared__ u16 msk[256];
  int mh = blockIdx.x, n = blockIdx.y, b = blockIdx.z;
  int tid = threadIdx.x;
  int w = tid >> 6, lane = tid & 63, ln = lane & 15, quad = lane >> 4;

  for (int i = tid; i < 1024; i += 256) w2s[(i>>6)*72 + (i&63)] = f2b(w_rp2[i]);
  if (tid < 16) b2s[tid] = b_rp2[tid];
  msk[tid] = (u16)(amask[b*N_ + mh*256 + tid] != 0);

  {
    float2 r01 = *(const float2*)(rel + ((size_t)((b*N_ + n)*N_) + mh*256 + tid)*2);
    const float* w1 = w_rp1;
    u16 hv[64];
    #pragma unroll
    for (int j=0;j<64;j++){
      float t = w1[2*j]*r01.x + w1[2*j+1]*r01.y + b_rp1[j];
      hv[j] = f2b(t > 0.f ? t : 0.f);
    }
    uint4* dst = (uint4*)&Hs[tid*72];
    #pragma unroll
    for (int c=0;c<8;c++) dst[c] = *(const uint4*)&hv[c*8];
  }
  __syncthreads();

  bf16x8 af0 = *(const bf16x8*)&w2s[ln*72 + quad*8];
  bf16x8 af1 = *(const bf16x8*)&w2s[ln*72 + 32 + quad*8];

  #pragma unroll
  for (int t=0; t<4; t++){
    int mt = w*4 + t;
    bf16x8 bf0 = *(const bf16x8*)&Hs[(mt*16+ln)*72 + quad*8];
    bf16x8 bf1 = *(const bf16x8*)&Hs[(mt*16+ln)*72 + 32 + quad*8];
    f32x4 c = {};
    c = __builtin_amdgcn_mfma_f32_16x16x32_bf16(af0, bf0, c, 0,0,0);
    c = __builtin_amdgcn_mfma_f32_16x16x32_bf16(af1, bf1, c, 0,0,0);
    bool valid = msk[mt*16 + ln] != 0;
    #pragma unroll
    for (int i=0;i<4;i++){
      int h = quad*4 + i;
      float val = valid ? (c[i] + b2s[h]) : -1e30f;
      Bs[h*272 + mt*16 + ln] = f2b(val);
    }
  }
  __syncthreads();

  #pragma unroll
  for (int it=0; it<8; it++){
    int idx = it*256 + tid;
    int r = idx >> 7, cc = idx & 127;
    size_t rb = (((size_t)(b*H_ + r)*N_) + n)*N_ + mh*256;
    ((unsigned int*)(biasbuf + rb))[cc] = ((const unsigned int*)(Bs + r*272))[cc];
  }
}

// ---------------- MFMA GEMM: 128x128 tile, BK=64, XOR-swizzled LDS.
// EPI_FC1: fused GELU -> bf16 [M,HID]. EPI_PART: split-K bf16 partials,
//   slice z -> (z<2 ? part01 : part23) + (z&1)*M*ldc.
enum { EPI_FC1=0, EPI_PART=1 };

template<int EPI>
__global__ __launch_bounds__(256) void k_gemm(const u16* __restrict__ A,
    const u16* __restrict__ W, const float* __restrict__ Wb, int K, int Kslice,
    int ldc, u16* __restrict__ part01, u16* __restrict__ part23)
{
  __shared__ __align__(16) u16 Al[128*64];
  __shared__ __align__(16) u16 Wl[128*64];
  int row0 = blockIdx.y*128, col0 = blockIdx.x*128;
  int tid = threadIdx.x;
  int w = tid >> 6, lane = tid & 63, ln = lane & 15, quad = lane >> 4;
  int wy = w >> 1, wx = w & 1;
  int srow = tid >> 3;
  int schunk = (tid & 7) ^ (srow & 7);
  const u16* Ag = A + (size_t)(row0 + srow)*K + schunk*8;
  const u16* Wg = W + (size_t)(col0 + srow)*K + schunk*8;
  int aoff[4][2], woff[4][2];
  #pragma unroll
  for (int ms=0; ms<4; ms++){
    int r = 64*wy + 16*ms + ln;
    #pragma unroll
    for (int kk=0; kk<2; kk++)
      aoff[ms][kk] = r*64 + (((kk*4+quad) ^ (ln&7))*8);
  }
  #pragma unroll
  for (int ns=0; ns<4; ns++){
    int r = 64*wx + 16*ns + ln;
    #pragma unroll
    for (int kk=0; kk<2; kk++)
      woff[ns][kk] = r*64 + (((kk*4+quad) ^ (ln&7))*8);
  }
  f32x4 acc[4][4] = {};
  int kbeg = blockIdx.z * Kslice;
  for (int k0 = kbeg; k0 < kbeg + Kslice; k0 += 64){
    #pragma unroll
    for (int i=0;i<4;i++){
      gload16(Ag + k0 + (size_t)(32*i)*K, Al + i*2048 + tid*8);
      gload16(Wg + k0 + (size_t)(32*i)*K, Wl + i*2048 + tid*8);
    }
    __syncthreads();
    #pragma unroll
    for (int kk=0; kk<2; kk++){
      bf16x8 af[4], bfr[4];
      #pragma unroll
      for (int ms=0; ms<4; ms++) af[ms]  = *(const bf16x8*)&Al[aoff[ms][kk]];
      #pragma unroll
      for (int ns=0; ns<4; ns++) bfr[ns] = *(const bf16x8*)&Wl[woff[ns][kk]];
      #pragma unroll
      for (int ms=0; ms<4; ms++)
        #pragma unroll
        for (int ns=0; ns<4; ns++)
          acc[ms][ns] = __builtin_amdgcn_mfma_f32_16x16x32_bf16(af[ms], bfr[ns], acc[ms][ns], 0,0,0);
    }
    __syncthreads();
  }

  u16* pbase = (EPI == EPI_PART)
             ? ((blockIdx.z < 2 ? part01 : part23) + (size_t)(blockIdx.z & 1)*M_*ldc)
             : part01;
  #pragma unroll
  for (int ms=0; ms<4; ms++){
    #pragma unroll
    for (int ns=0; ns<4; ns++){
      int c = col0 + 64*wx + 16*ns + ln;
      float wb = (EPI == EPI_FC1) ? Wb[c] : 0.f;
      #pragma unroll
      for (int i=0;i<4;i++){
        int r = row0 + 64*wy + 16*ms + quad*4 + i;
        float val = acc[ms][ns][i] + wb;
        if (EPI == EPI_FC1){
          float gl = 0.5f*val*(1.f + erff(val*0.70710678f));
          pbase[(size_t)r*ldc + c] = f2b(gl);
        } else {
          pbase[(size_t)r*ldc + c] = f2b(val);
        }
      }
    }
  }
}

// ---------------- QKV reduce: qkv = part0+part1 + b_qkv -> bf16 [M,3072]
__global__ __launch_bounds__(256) void k_redq(const u16* __restrict__ part,
    const float* __restrict__ Wb, u16* __restrict__ qkvb)
{
  size_t i = ((size_t)blockIdx.x*256 + threadIdx.x)*4;
  int c = (int)(i % 3072);
  uint2 p0 = *(const uint2*)(part + i);
  uint2 p1 = *(const uint2*)(part + (size_t)M_*3072 + i);
  float4 bi = *(const float4*)(Wb + c);
  u16 o[4];
  o[0] = f2b(b2f((u16)(p0.x & 0xffff)) + b2f((u16)(p1.x & 0xffff)) + bi.x);
  o[1] = f2b(b2f((u16)(p0.x >> 16))    + b2f((u16)(p1.x >> 16))    + bi.y);
  o[2] = f2b(b2f((u16)(p0.y & 0xffff)) + b2f((u16)(p1.y & 0xffff)) + bi.z);
  o[3] = f2b(b2f((u16)(p0.y >> 16))    + b2f((u16)(p1.y >> 16))    + bi.w);
  *(uint2*)(qkvb + i) = *(const uint2*)o;
}

// ---------------- 4-slice reduce + bias + gate + residual -> f32
template<int GIDX>
__global__ __launch_bounds__(256) void k_red4(const u16* __restrict__ p01,
    const u16* __restrict__ p23, const float* __restrict__ Wb,
    const float* __restrict__ mod, const float* __restrict__ resid,
    float* __restrict__ outp)
{
  size_t i = ((size_t)blockIdx.x*256 + threadIdx.x)*4;
  int c = (int)(i & 1023); int r = (int)(i >> 10); int b = r >> 9;
  uint2 a0 = *(const uint2*)(p01 + i);
  uint2 a1 = *(const uint2*)(p01 + (size_t)M_*D_ + i);
  uint2 a2 = *(const uint2*)(p23 + i);
  uint2 a3 = *(const uint2*)(p23 + (size_t)M_*D_ + i);
  float4 pv;
  pv.x = b2f((u16)(a0.x&0xffff)) + b2f((u16)(a1.x&0xffff)) + b2f((u16)(a2.x&0xffff)) + b2f((u16)(a3.x&0xffff));
  pv.y = b2f((u16)(a0.x>>16))    + b2f((u16)(a1.x>>16))    + b2f((u16)(a2.x>>16))    + b2f((u16)(a3.x>>16));
  pv.z = b2f((u16)(a0.y&0xffff)) + b2f((u16)(a1.y&0xffff)) + b2f((u16)(a2.y&0xffff)) + b2f((u16)(a3.y&0xffff));
  pv.w = b2f((u16)(a0.y>>16))    + b2f((u16)(a1.y>>16))    + b2f((u16)(a2.y>>16))    + b2f((u16)(a3.y>>16));
  float4 x4 = *(const float4*)(resid + i);
  float4 bi = *(const float4*)(Wb + c);
  float4 g4 = *(const float4*)(mod + b*6*D_ + GIDX*D_ + c);
  float4 o;
  o.x = x4.x + g4.x*(pv.x + bi.x);
  o.y = x4.y + g4.y*(pv.y + bi.y);
  o.z = x4.z + g4.z*(pv.z + bi.z);
  o.w = x4.w + g4.w*(pv.w + bi.w);
  *(float4*)(outp + i) = o;
}

// ---------------- flash attention: block = (nt64, h, b), 4 waves, 64 q-rows
__global__ __launch_bounds__(256) void k_attn(const u16* __restrict__ qkv,
    const u16* __restrict__ biasbuf, u16* __restrict__ attn_out)
{
  __shared__ __align__(16) u16 Qs[64*72];
  __shared__ __align__(16) u16 Ks[64*72];
  __shared__ __align__(16) u16 Vt[64*72];
  __shared__ __align__(16) u16 Ps[4*16*72];
  int nt = blockIdx.x, h = blockIdx.y, b = blockIdx.z;
  int n0 = nt*64;
  int tid = threadIdx.x;
  int w = tid >> 6, lane = tid & 63, ln = lane & 15, quad = lane >> 4;

  {
    int row = tid >> 2, cb = (tid & 3)*16;
    const u16* src = qkv + (size_t)(b*N_ + n0 + row)*3072 + h*64 + cb;
    uint4 q0 = *(const uint4*)src, q1 = *(const uint4*)(src+8);
    uint4* dst = (uint4*)&Qs[row*72 + cb];
    dst[0] = q0; dst[1] = q1;
  }
  __syncthreads();
  bf16x8 qf[2];
  qf[0] = *(const bf16x8*)&Qs[(16*w+ln)*72 + quad*8];
  qf[1] = *(const bf16x8*)&Qs[(16*w+ln)*72 + 32 + quad*8];

  f32x4 oacc[4] = {};
  float rmax[4] = {-3e38f,-3e38f,-3e38f,-3e38f};
  float rsum[4] = {0.f,0.f,0.f,0.f};
  const u16* bp = biasbuf + (((size_t)(b*H_ + h)*N_) + n0 + 16*w)*N_ + ln;

  for (int mt = 0; mt < 8; mt++){
    __syncthreads();
    {
      int r = tid >> 2, cb = (tid & 3)*16;
      const u16* kp = qkv + (size_t)(b*N_ + mt*64 + r)*3072 + 1024 + h*64 + cb;
      uint4 k0 = *(const uint4*)kp, k1 = *(const uint4*)(kp+8);
      uint4* kd = (uint4*)&Ks[r*72 + cb];
      kd[0] = k0; kd[1] = k1;
      const u16* vp = qkv + (size_t)(b*N_ + mt*64 + r)*3072 + 2048 + h*64 + cb;
      uint4 v0 = *(const uint4*)vp, v1 = *(const uint4*)(vp+8);
      u16 ve[16];
      *(uint4*)&ve[0] = v0; *(uint4*)&ve[8] = v1;
      #pragma unroll
      for (int j=0;j<16;j++) Vt[(cb+j)*72 + r] = ve[j];
    }
    __syncthreads();

    u16 bl[4][4];
    #pragma unroll
    for (int cs=0; cs<4; cs++)
      #pragma unroll
      for (int i=0;i<4;i++)
        bl[cs][i] = bp[(size_t)(quad*4+i)*N_ + mt*64 + 16*cs];

    f32x4 s[4];
    #pragma unroll
    for (int cs=0; cs<4; cs++){
      bf16x8 k0f = *(const bf16x8*)&Ks[(16*cs+ln)*72 + quad*8];
      bf16x8 k1f = *(const bf16x8*)&Ks[(16*cs+ln)*72 + 32 + quad*8];
      f32x4 z = {};
      z = __builtin_amdgcn_mfma_f32_16x16x32_bf16(qf[0], k0f, z, 0,0,0);
      z = __builtin_amdgcn_mfma_f32_16x16x32_bf16(qf[1], k1f, z, 0,0,0);
      s[cs] = z;
    }
    #pragma unroll
    for (int cs=0; cs<4; cs++)
      #pragma unroll
      for (int i=0;i<4;i++)
        s[cs][i] = s[cs][i]*0.125f + b2f(bl[cs][i]);

    #pragma unroll
    for (int i=0;i<4;i++){
      float tm = fmaxf(fmaxf(s[0][i], s[1][i]), fmaxf(s[2][i], s[3][i]));
      #pragma unroll
      for (int o=1;o<16;o<<=1) tm = fmaxf(tm, __shfl_xor(tm, o));
      float nm = fmaxf(rmax[i], tm);
      float alpha = __expf(rmax[i] - nm);
      rmax[i] = nm;
      float ps = 0.f;
      #pragma unroll
      for (int cs=0; cs<4; cs++){
        float p = __expf(s[cs][i] - nm);
        s[cs][i] = p; ps += p;
      }
      #pragma unroll
      for (int o=1;o<16;o<<=1) ps += __shfl_xor(ps, o);
      rsum[i] = rsum[i]*alpha + ps;
      #pragma unroll
      for (int ds=0; ds<4; ds++) oacc[ds][i] *= alpha;
    }

    #pragma unroll
    for (int cs=0; cs<4; cs++)
      #pragma unroll
      for (int i=0;i<4;i++)
        Ps[w*1152 + (quad*4+i)*72 + 16*cs + ln] = f2b(s[cs][i]);

    bf16x8 pf0 = *(const bf16x8*)&Ps[w*1152 + ln*72 + quad*8];
    bf16x8 pf1 = *(const bf16x8*)&Ps[w*1152 + ln*72 + 32 + quad*8];
    #pragma unroll
    for (int ds=0; ds<4; ds++){
      bf16x8 v0f = *(const bf16x8*)&Vt[(16*ds+ln)*72 + quad*8];
      bf16x8 v1f = *(const bf16x8*)&Vt[(16*ds+ln)*72 + 32 + quad*8];
      oacc[ds] = __builtin_amdgcn_mfma_f32_16x16x32_bf16(pf0, v0f, oacc[ds], 0,0,0);
      oacc[ds] = __builtin_amdgcn_mfma_f32_16x16x32_bf16(pf1, v1f, oacc[ds], 0,0,0);
    }
  }

  #pragma unroll
  for (int i=0;i<4;i++){
    float inv = 1.f / rsum[i];
    int r = b*N_ + n0 + 16*w + quad*4 + i;
    #pragma unroll
    for (int ds=0; ds<4; ds++)
      attn_out[(size_t)r*D_ + h*64 + 16*ds + ln] = f2b(oacc[ds][i]*inv);
  }
}

extern "C" void kernel_launch(void* const* d_in, const int* in_sizes, int n_in,
                              void* d_out, int out_size, void* d_ws, size_t ws_size,
                              hipStream_t stream) {
  const float* x      = (const float*)d_in[0];
  const float* t_emb  = (const float*)d_in[1];
  const float* rel    = (const float*)d_in[2];
  const int*   amask  = (const int*)d_in[3];
  const float* w_ada  = (const float*)d_in[4];
  const float* b_ada  = (const float*)d_in[5];
  const float* g1     = (const float*)d_in[6];
  const float* beta1  = (const float*)d_in[7];
  const float* g2     = (const float*)d_in[8];
  const float* beta2  = (const float*)d_in[9];
  const float* w_qkv  = (const float*)d_in[10];
  const float* b_qkv  = (const float*)d_in[11];
  const float* w_proj = (const float*)d_in[12];
  const float* b_proj = (const float*)d_in[13];
  const float* w_rp1  = (const float*)d_in[14];
  const float* b_rp1  = (const float*)d_in[15];
  const float* w_rp2  = (const float*)d_in[16];
  const float* b_rp2  = (const float*)d_in[17];
  const float* w_fc1  = (const float*)d_in[18];
  const float* b_fc1  = (const float*)d_in[19];
  const float* w_fc2  = (const float*)d_in[20];
  const float* b_fc2  = (const float*)d_in[21];
  float* outp = (float*)d_out;

  const size_t MB = 1u<<20;
  char* wsb = (char*)d_ws;
  float* mod   = (float*)(wsb);
  u16*  xn     = (u16*) (wsb + 131072);
  float* xm    = (float*)(wsb + 131072 + 4*MB);
  u16*  wqkvb  = (u16*) (wsb + 131072 + 12*MB);
  u16*  wprojb = (u16*) (wsb + 131072 + 18*MB);
  u16*  partb  = (u16*) (wsb + 131072 + 20*MB);       // 8 MB (2 x [M,1024])
  char*  S     = wsb + 131072 + 28*MB;
  u16*  qkvb   = (u16*)(S);                           // [M,3072] 12 MB
  u16*  qkvpart= (u16*)(S + 12*MB);                   // 2 x [M,3072] = 24 MB
  u16*  biasb  = (u16*)(S + 12*MB);                   // [B,H,N,N] 32 MB (after redq)
  u16*  projp23= (u16*)(S);                           // PROJ partials 2,3 (qkvb dead)
  u16*  hb     = (u16*)(S);                           // [M,4096] 16 MB (phase B)
  u16*  wfc1b  = (u16*)(S + 16*MB);
  u16*  wfc2b  = (u16*)(S + 24*MB);
  u16*  fc2p23 = (u16*)(S + 32*MB);                   // FC2 partials 2,3 (8 MB)

  k_cvt2<<<2048, 256, 0, stream>>>(w_qkv, wqkvb, 1536, w_proj, wprojb);
  k_mod<<<dim3(6*D_/256, B_), 256, 0, stream>>>(t_emb, w_ada, b_ada, mod);
  k_lnmod<<<M_, 256, 0, stream>>>(x, g1, beta1, mod, 0, 1, xn);
  // QKV split-K x2 -> partials in (future) biasb region -> reduce+bias -> qkvb
  k_gemm<EPI_PART><<<dim3(3072/128, M_/128, 2), 256, 0, stream>>>(
      xn, wqkvb, nullptr, D_, D_/2, 3072, qkvpart, qkvpart);
  k_redq<<<6144, 256, 0, stream>>>(qkvpart, b_qkv, qkvb);
  k_bias<<<dim3(2, N_, B_), 256, 0, stream>>>(rel, amask, w_rp1, b_rp1, w_rp2, b_rp2, biasb);
  k_attn<<<dim3(8, H_, B_), 256, 0, stream>>>(qkvb, biasb, xn);
  k_cvt2<<<4096, 256, 0, stream>>>(w_fc1, wfc1b, 2048, w_fc2, wfc2b);
  // PROJ split-K x4
  k_gemm<EPI_PART><<<dim3(D_/128, M_/128, 4), 256, 0, stream>>>(
      xn, wprojb, nullptr, D_, D_/4, D_, partb, projp23);
  k_red4<2><<<2048, 256, 0, stream>>>(partb, projp23, b_proj, mod, x, xm);
  k_lnmod<<<M_, 256, 0, stream>>>(xm, g2, beta2, mod, 3, 4, xn);
  k_gemm<EPI_FC1><<<dim3(HID_/128, M_/128), 256, 0, stream>>>(
      xn, wfc1b, b_fc1, D_, D_, HID_, hb, nullptr);
  // FC2 split-K x4
  k_gemm<EPI_PART><<<dim3(D_/128, M_/128, 4), 256, 0, stream>>>(
      hb, wfc2b, nullptr, HID_, HID_/4, D_, partb, fc2p23);
  k_red4<5><<<2048, 256, 0, stream>>>(partb, fc2p23, b_fc2, mod, xm, outp);
}

// Round 8
// 356.880 us; speedup vs baseline: 5.4142x; 1.0354x over previous
//
#include <hip/hip_runtime.h>

// DiT block, B=4 N=512 D=1024 H=16 HD=64 HID=4096 RP_HID=64. All f32 I/O.
// R8: QKV/FC1 as 64x128-tile direct GEMMs (3-4 blocks/CU, no partials);
//     PROJ-reduce fused with LN2; PROJ/FC2 stay split-K x4.
// ws (byte off): mod@0 | xn@128K | xm@128K+4M | wqkvb@+12M | wprojb@+18M |
//   partb@+20M (8M) | S@+28M (44M):
//     qkvb @S (12M) | biasb @S+12M (32M)
//     projp23 @S (8M, qkvb dead) | hb @S (16M) | wfc1b @S+16M | wfc2b @S+24M
//     fc2p23 @S+32M (8M, biasb dead)

#define B_ 4
#define N_ 512
#define D_ 1024
#define H_ 16
#define HID_ 4096
#define M_ (B_*N_)

typedef unsigned short u16;
typedef __attribute__((ext_vector_type(8))) short bf16x8;
typedef __attribute__((ext_vector_type(4))) float f32x4;

__device__ __forceinline__ float b2f(u16 u){
  union { unsigned int i; float f; } x; x.i = ((unsigned int)u) << 16; return x.f;
}
__device__ __forceinline__ u16 f2b(float f){          // RNE
  unsigned int u = __float_as_uint(f);
  return (u16)((u + 0x7fffu + ((u >> 16) & 1u)) >> 16);
}

__device__ __forceinline__ void gload16(const u16* __restrict__ g, u16* l){
#if defined(__has_builtin) && __has_builtin(__builtin_amdgcn_global_load_lds)
  __builtin_amdgcn_global_load_lds(
      (const __attribute__((address_space(1))) unsigned int*)g,
      (__attribute__((address_space(3))) unsigned int*)l, 16, 0, 0);
#else
  *(uint4*)l = *(const uint4*)g;
#endif
}

// ---------------- f32 -> bf16 convert, two tensors in one launch
__global__ __launch_bounds__(256) void k_cvt2(const float* __restrict__ sA, u16* __restrict__ dA,
    int nA, const float* __restrict__ sB, u16* __restrict__ dB){
  int blk = blockIdx.x;
  const float* s; u16* d; size_t i;
  if (blk < nA){ s = sA; d = dA; i = ((size_t)blk*256 + threadIdx.x)*8; }
  else { s = sB; d = dB; i = ((size_t)(blk-nA)*256 + threadIdx.x)*8; }
  float4 a = *(const float4*)(s+i), b = *(const float4*)(s+i+4);
  u16 o[8] = {f2b(a.x),f2b(a.y),f2b(a.z),f2b(a.w),f2b(b.x),f2b(b.y),f2b(b.z),f2b(b.w)};
  *(uint4*)(d+i) = *(const uint4*)o;
}

// ---------------- adaLN modulation
__global__ __launch_bounds__(256) void k_mod(const float* __restrict__ t_emb,
    const float* __restrict__ w_ada, const float* __restrict__ b_ada,
    float* __restrict__ mod)
{
  __shared__ float st[D_];
  int b = blockIdx.y;
  for (int i = threadIdx.x; i < D_; i += 256){
    float x = t_emb[b*D_ + i];
    st[i] = x / (1.f + __expf(-x));
  }
  __syncthreads();
  int j = blockIdx.x * 256 + threadIdx.x;
  const float* wr = w_ada + (size_t)j * D_;
  float acc = b_ada[j];
  for (int k = 0; k < D_; k += 8){
    float4 p0 = *(const float4*)(wr + k);
    float4 p1 = *(const float4*)(wr + k + 4);
    acc += p0.x*st[k+0] + p0.y*st[k+1] + p0.z*st[k+2] + p0.w*st[k+3];
    acc += p1.x*st[k+4] + p1.y*st[k+5] + p1.z*st[k+6] + p1.w*st[k+7];
  }
  mod[b*6*D_ + j] = acc;
}

// ---------------- LayerNorm + adaLN modulate -> bf16 (LN1)
__global__ __launch_bounds__(256) void k_lnmod(const float* __restrict__ xin,
    const float* __restrict__ g, const float* __restrict__ be,
    const float* __restrict__ mod, int shift_idx, int scale_idx,
    u16* __restrict__ xn)
{
  int row = blockIdx.x;
  int b = row >> 9;
  float v[4]; float s = 0.f, s2 = 0.f;
  #pragma unroll
  for (int i=0;i<4;i++){
    float x = xin[(size_t)row*D_ + threadIdx.x + i*256];
    v[i] = x; s += x; s2 += x*x;
  }
  #pragma unroll
  for (int o=32;o>0;o>>=1){ s += __shfl_down(s,o); s2 += __shfl_down(s2,o); }
  __shared__ float rs[4], rs2[4];
  int w = threadIdx.x >> 6;
  if ((threadIdx.x & 63)==0){ rs[w]=s; rs2[w]=s2; }
  __syncthreads();
  s = rs[0]+rs[1]+rs[2]+rs[3]; s2 = rs2[0]+rs2[1]+rs2[2]+rs2[3];
  float mu = s * (1.f/D_);
  float var = s2 * (1.f/D_) - mu*mu;
  float rstd = rsqrtf(var + 1e-5f);
  const float* mrow = mod + b*6*D_;
  #pragma unroll
  for (int i=0;i<4;i++){
    int d = threadIdx.x + i*256;
    float xg = (v[i]-mu)*rstd*g[d] + be[d];
    xn[(size_t)row*D_ + d] = f2b(xg * (1.f + mrow[scale_idx*D_ + d]) + mrow[shift_idx*D_ + d]);
  }
}

// ---------------- rel-pos bias MLP -> bf16 bias[b,h,n,m]
__global__ __launch_bounds__(256) void k_bias(const float* __restrict__ rel,
    const int* __restrict__ amask,
    const float* __restrict__ w_rp1, const float* __restrict__ b_rp1,
    const float* __restrict__ w_rp2, const float* __restrict__ b_rp2,
    u16* __restrict__ biasbuf)
{
  __shared__ __align__(16) u16 Hs[256*72];
  __shared__ __align__(16) u16 Bs[16*272];
  __shared__ __align__(16) u16 w2s[16*72];
  __shared__ float b2s[16];
  __shared__ u16 msk[256];
  int mh = blockIdx.x, n = blockIdx.y, b = blockIdx.z;
  int tid = threadIdx.x;
  int w = tid >> 6, lane = tid & 63, ln = lane & 15, quad = lane >> 4;

  for (int i = tid; i < 1024; i += 256) w2s[(i>>6)*72 + (i&63)] = f2b(w_rp2[i]);
  if (tid < 16) b2s[tid] = b_rp2[tid];
  msk[tid] = (u16)(amask[b*N_ + mh*256 + tid] != 0);

  {
    float2 r01 = *(const float2*)(rel + ((size_t)((b*N_ + n)*N_) + mh*256 + tid)*2);
    const float* w1 = w_rp1;
    u16 hv[64];
    #pragma unroll
    for (int j=0;j<64;j++){
      float t = w1[2*j]*r01.x + w1[2*j+1]*r01.y + b_rp1[j];
      hv[j] = f2b(t > 0.f ? t : 0.f);
    }
    uint4* dst = (uint4*)&Hs[tid*72];
    #pragma unroll
    for (int c=0;c<8;c++) dst[c] = *(const uint4*)&hv[c*8];
  }
  __syncthreads();

  bf16x8 af0 = *(const bf16x8*)&w2s[ln*72 + quad*8];
  bf16x8 af1 = *(const bf16x8*)&w2s[ln*72 + 32 + quad*8];

  #pragma unroll
  for (int t=0; t<4; t++){
    int mt = w*4 + t;
    bf16x8 bf0 = *(const bf16x8*)&Hs[(mt*16+ln)*72 + quad*8];
    bf16x8 bf1 = *(const bf16x8*)&Hs[(mt*16+ln)*72 + 32 + quad*8];
    f32x4 c = {};
    c = __builtin_amdgcn_mfma_f32_16x16x32_bf16(af0, bf0, c, 0,0,0);
    c = __builtin_amdgcn_mfma_f32_16x16x32_bf16(af1, bf1, c, 0,0,0);
    bool valid = msk[mt*16 + ln] != 0;
    #pragma unroll
    for (int i=0;i<4;i++){
      int h = quad*4 + i;
      float val = valid ? (c[i] + b2s[h]) : -1e30f;
      Bs[h*272 + mt*16 + ln] = f2b(val);
    }
  }
  __syncthreads();

  #pragma unroll
  for (int it=0; it<8; it++){
    int idx = it*256 + tid;
    int r = idx >> 7, cc = idx & 127;
    size_t rb = (((size_t)(b*H_ + r)*N_) + n)*N_ + mh*256;
    ((unsigned int*)(biasbuf + rb))[cc] = ((const unsigned int*)(Bs + r*272))[cc];
  }
}

// ---------------- 64x128-tile MFMA GEMM, BK=64, XOR-swizzle, direct epilogue.
enum { EPI_PLAIN=0, EPI_GELU=1 };

template<int EPI>
__global__ __launch_bounds__(256) void k_gemm64(const u16* __restrict__ A,
    const u16* __restrict__ W, const float* __restrict__ Wb, int K, int ldc,
    u16* __restrict__ o_u16)
{
  __shared__ __align__(16) u16 Al[64*64];    //  8 KB
  __shared__ __align__(16) u16 Wl[128*64];   // 16 KB
  int row0 = blockIdx.y*64, col0 = blockIdx.x*128;
  int tid = threadIdx.x;
  int w = tid >> 6, lane = tid & 63, ln = lane & 15, quad = lane >> 4;
  int wy = w >> 1, wx = w & 1;
  int srow = tid >> 3;
  int schunk = (tid & 7) ^ (srow & 7);
  const u16* Ag = A + (size_t)(row0 + srow)*K + schunk*8;
  const u16* Wg = W + (size_t)(col0 + srow)*K + schunk*8;
  int aoff[2][2], woff[4][2];
  #pragma unroll
  for (int ms=0; ms<2; ms++){
    int r = 32*wy + 16*ms + ln;
    #pragma unroll
    for (int kk=0; kk<2; kk++)
      aoff[ms][kk] = r*64 + (((kk*4+quad) ^ (ln&7))*8);
  }
  #pragma unroll
  for (int ns=0; ns<4; ns++){
    int r = 64*wx + 16*ns + ln;
    #pragma unroll
    for (int kk=0; kk<2; kk++)
      woff[ns][kk] = r*64 + (((kk*4+quad) ^ (ln&7))*8);
  }
  f32x4 acc[2][4] = {};
  for (int k0 = 0; k0 < K; k0 += 64){
    gload16(Ag + k0,                  Al + tid*8);
    gload16(Ag + k0 + (size_t)32*K,   Al + 2048 + tid*8);
    #pragma unroll
    for (int i=0;i<4;i++)
      gload16(Wg + k0 + (size_t)(32*i)*K, Wl + i*2048 + tid*8);
    __syncthreads();
    #pragma unroll
    for (int kk=0; kk<2; kk++){
      bf16x8 af[2], bfr[4];
      #pragma unroll
      for (int ms=0; ms<2; ms++) af[ms]  = *(const bf16x8*)&Al[aoff[ms][kk]];
      #pragma unroll
      for (int ns=0; ns<4; ns++) bfr[ns] = *(const bf16x8*)&Wl[woff[ns][kk]];
      #pragma unroll
      for (int ms=0; ms<2; ms++)
        #pragma unroll
        for (int ns=0; ns<4; ns++)
          acc[ms][ns] = __builtin_amdgcn_mfma_f32_16x16x32_bf16(af[ms], bfr[ns], acc[ms][ns], 0,0,0);
    }
    __syncthreads();
  }
  #pragma unroll
  for (int ms=0; ms<2; ms++){
    #pragma unroll
    for (int ns=0; ns<4; ns++){
      int c = col0 + 64*wx + 16*ns + ln;
      float wb = Wb[c];
      #pragma unroll
      for (int i=0;i<4;i++){
        int r = row0 + 32*wy + 16*ms + quad*4 + i;
        float val = acc[ms][ns][i] + wb;
        if (EPI == EPI_GELU) val = 0.5f*val*(1.f + erff(val*0.70710678f));
        o_u16[(size_t)r*ldc + c] = f2b(val);
      }
    }
  }
}

// ---------------- 128x128-tile split-K GEMM -> bf16 partials
__global__ __launch_bounds__(256) void k_gemm(const u16* __restrict__ A,
    const u16* __restrict__ W, int K, int Kslice,
    int ldc, u16* __restrict__ part01, u16* __restrict__ part23)
{
  __shared__ __align__(16) u16 Al[128*64];
  __shared__ __align__(16) u16 Wl[128*64];
  int row0 = blockIdx.y*128, col0 = blockIdx.x*128;
  int tid = threadIdx.x;
  int w = tid >> 6, lane = tid & 63, ln = lane & 15, quad = lane >> 4;
  int wy = w >> 1, wx = w & 1;
  int srow = tid >> 3;
  int schunk = (tid & 7) ^ (srow & 7);
  const u16* Ag = A + (size_t)(row0 + srow)*K + schunk*8;
  const u16* Wg = W + (size_t)(col0 + srow)*K + schunk*8;
  int aoff[4][2], woff[4][2];
  #pragma unroll
  for (int ms=0; ms<4; ms++){
    int r = 64*wy + 16*ms + ln;
    #pragma unroll
    for (int kk=0; kk<2; kk++)
      aoff[ms][kk] = r*64 + (((kk*4+quad) ^ (ln&7))*8);
  }
  #pragma unroll
  for (int ns=0; ns<4; ns++){
    int r = 64*wx + 16*ns + ln;
    #pragma unroll
    for (int kk=0; kk<2; kk++)
      woff[ns][kk] = r*64 + (((kk*4+quad) ^ (ln&7))*8);
  }
  f32x4 acc[4][4] = {};
  int kbeg = blockIdx.z * Kslice;
  for (int k0 = kbeg; k0 < kbeg + Kslice; k0 += 64){
    #pragma unroll
    for (int i=0;i<4;i++){
      gload16(Ag + k0 + (size_t)(32*i)*K, Al + i*2048 + tid*8);
      gload16(Wg + k0 + (size_t)(32*i)*K, Wl + i*2048 + tid*8);
    }
    __syncthreads();
    #pragma unroll
    for (int kk=0; kk<2; kk++){
      bf16x8 af[4], bfr[4];
      #pragma unroll
      for (int ms=0; ms<4; ms++) af[ms]  = *(const bf16x8*)&Al[aoff[ms][kk]];
      #pragma unroll
      for (int ns=0; ns<4; ns++) bfr[ns] = *(const bf16x8*)&Wl[woff[ns][kk]];
      #pragma unroll
      for (int ms=0; ms<4; ms++)
        #pragma unroll
        for (int ns=0; ns<4; ns++)
          acc[ms][ns] = __builtin_amdgcn_mfma_f32_16x16x32_bf16(af[ms], bfr[ns], acc[ms][ns], 0,0,0);
    }
    __syncthreads();
  }
  u16* pbase = (blockIdx.z < 2 ? part01 : part23) + (size_t)(blockIdx.z & 1)*M_*ldc;
  #pragma unroll
  for (int ms=0; ms<4; ms++){
    #pragma unroll
    for (int ns=0; ns<4; ns++){
      int c = col0 + 64*wx + 16*ns + ln;
      #pragma unroll
      for (int i=0;i<4;i++){
        int r = row0 + 64*wy + 16*ms + quad*4 + i;
        pbase[(size_t)r*ldc + c] = f2b(acc[ms][ns][i]);
      }
    }
  }
}

// ---------------- 4-slice reduce + bias + gate + residual -> f32 out (FC2 final)
template<int GIDX>
__global__ __launch_bounds__(256) void k_red4(const u16* __restrict__ p01,
    const u16* __restrict__ p23, const float* __restrict__ Wb,
    const float* __restrict__ mod, const float* __restrict__ resid,
    float* __restrict__ outp)
{
  size_t i = ((size_t)blockIdx.x*256 + threadIdx.x)*4;
  int c = (int)(i & 1023); int r = (int)(i >> 10); int b = r >> 9;
  uint2 a0 = *(const uint2*)(p01 + i);
  uint2 a1 = *(const uint2*)(p01 + (size_t)M_*D_ + i);
  uint2 a2 = *(const uint2*)(p23 + i);
  uint2 a3 = *(const uint2*)(p23 + (size_t)M_*D_ + i);
  float4 pv;
  pv.x = b2f((u16)(a0.x&0xffff)) + b2f((u16)(a1.x&0xffff)) + b2f((u16)(a2.x&0xffff)) + b2f((u16)(a3.x&0xffff));
  pv.y = b2f((u16)(a0.x>>16))    + b2f((u16)(a1.x>>16))    + b2f((u16)(a2.x>>16))    + b2f((u16)(a3.x>>16));
  pv.z = b2f((u16)(a0.y&0xffff)) + b2f((u16)(a1.y&0xffff)) + b2f((u16)(a2.y&0xffff)) + b2f((u16)(a3.y&0xffff));
  pv.w = b2f((u16)(a0.y>>16))    + b2f((u16)(a1.y>>16))    + b2f((u16)(a2.y>>16))    + b2f((u16)(a3.y>>16));
  float4 x4 = *(const float4*)(resid + i);
  float4 bi = *(const float4*)(Wb + c);
  float4 g4 = *(const float4*)(mod + b*6*D_ + GIDX*D_ + c);
  float4 o;
  o.x = x4.x + g4.x*(pv.x + bi.x);
  o.y = x4.y + g4.y*(pv.y + bi.y);
  o.z = x4.z + g4.z*(pv.z + bi.z);
  o.w = x4.w + g4.w*(pv.w + bi.w);
  *(float4*)(outp + i) = o;
}

// ---------------- PROJ reduce + gate_s + residual -> xm, then LN2+mod -> xn
__global__ __launch_bounds__(256) void k_redln(const u16* __restrict__ p01,
    const u16* __restrict__ p23, const float* __restrict__ Wb,
    const float* __restrict__ mod, const float* __restrict__ resid,
    const float* __restrict__ g, const float* __restrict__ be,
    float* __restrict__ xm, u16* __restrict__ xn)
{
  int row = blockIdx.x, b = row >> 9, tid = threadIdx.x;
  size_t i = (size_t)row*D_ + tid*4;
  int c = tid*4;
  uint2 a0 = *(const uint2*)(p01 + i);
  uint2 a1 = *(const uint2*)(p01 + (size_t)M_*D_ + i);
  uint2 a2 = *(const uint2*)(p23 + i);
  uint2 a3 = *(const uint2*)(p23 + (size_t)M_*D_ + i);
  float4 pv;
  pv.x = b2f((u16)(a0.x&0xffff)) + b2f((u16)(a1.x&0xffff)) + b2f((u16)(a2.x&0xffff)) + b2f((u16)(a3.x&0xffff));
  pv.y = b2f((u16)(a0.x>>16))    + b2f((u16)(a1.x>>16))    + b2f((u16)(a2.x>>16))    + b2f((u16)(a3.x>>16));
  pv.z = b2f((u16)(a0.y&0xffff)) + b2f((u16)(a1.y&0xffff)) + b2f((u16)(a2.y&0xffff)) + b2f((u16)(a3.y&0xffff));
  pv.w = b2f((u16)(a0.y>>16))    + b2f((u16)(a1.y>>16))    + b2f((u16)(a2.y>>16))    + b2f((u16)(a3.y>>16));
  float4 x4 = *(const float4*)(resid + i);
  float4 bi = *(const float4*)(Wb + c);
  float4 g4 = *(const float4*)(mod + b*6*D_ + 2*D_ + c);
  float4 mid;
  mid.x = x4.x + g4.x*(pv.x + bi.x);
  mid.y = x4.y + g4.y*(pv.y + bi.y);
  mid.z = x4.z + g4.z*(pv.z + bi.z);
  mid.w = x4.w + g4.w*(pv.w + bi.w);
  *(float4*)(xm + i) = mid;
  // LN2
  float s = mid.x+mid.y+mid.z+mid.w;
  float s2 = mid.x*mid.x+mid.y*mid.y+mid.z*mid.z+mid.w*mid.w;
  #pragma unroll
  for (int o=32;o>0;o>>=1){ s += __shfl_down(s,o); s2 += __shfl_down(s2,o); }
  __shared__ float rs[4], rs2[4];
  int w = tid >> 6;
  if ((tid & 63)==0){ rs[w]=s; rs2[w]=s2; }
  __syncthreads();
  s = rs[0]+rs[1]+rs[2]+rs[3]; s2 = rs2[0]+rs2[1]+rs2[2]+rs2[3];
  float mu = s * (1.f/D_);
  float var = s2 * (1.f/D_) - mu*mu;
  float rstd = rsqrtf(var + 1e-5f);
  const float* mrow = mod + b*6*D_;
  float4 gg = *(const float4*)(g + c);
  float4 bb = *(const float4*)(be + c);
  float4 sc = *(const float4*)(mrow + 4*D_ + c);
  float4 sh = *(const float4*)(mrow + 3*D_ + c);
  u16 o[4];
  o[0] = f2b(((mid.x-mu)*rstd*gg.x + bb.x)*(1.f+sc.x) + sh.x);
  o[1] = f2b(((mid.y-mu)*rstd*gg.y + bb.y)*(1.f+sc.y) + sh.y);
  o[2] = f2b(((mid.z-mu)*rstd*gg.z + bb.z)*(1.f+sc.z) + sh.z);
  o[3] = f2b(((mid.w-mu)*rstd*gg.w + bb.w)*(1.f+sc.w) + sh.w);
  *(uint2*)(xn + i) = *(const uint2*)o;
}

// ---------------- flash attention: block = (nt64, h, b), 4 waves, 64 q-rows
__global__ __launch_bounds__(256) void k_attn(const u16* __restrict__ qkv,
    const u16* __restrict__ biasbuf, u16* __restrict__ attn_out)
{
  __shared__ __align__(16) u16 Qs[64*72];
  __shared__ __align__(16) u16 Ks[64*72];
  __shared__ __align__(16) u16 Vt[64*72];
  __shared__ __align__(16) u16 Ps[4*16*72];
  int nt = blockIdx.x, h = blockIdx.y, b = blockIdx.z;
  int n0 = nt*64;
  int tid = threadIdx.x;
  int w = tid >> 6, lane = tid & 63, ln = lane & 15, quad = lane >> 4;

  {
    int row = tid >> 2, cb = (tid & 3)*16;
    const u16* src = qkv + (size_t)(b*N_ + n0 + row)*3072 + h*64 + cb;
    uint4 q0 = *(const uint4*)src, q1 = *(const uint4*)(src+8);
    uint4* dst = (uint4*)&Qs[row*72 + cb];
    dst[0] = q0; dst[1] = q1;
  }
  __syncthreads();
  bf16x8 qf[2];
  qf[0] = *(const bf16x8*)&Qs[(16*w+ln)*72 + quad*8];
  qf[1] = *(const bf16x8*)&Qs[(16*w+ln)*72 + 32 + quad*8];

  f32x4 oacc[4] = {};
  float rmax[4] = {-3e38f,-3e38f,-3e38f,-3e38f};
  float rsum[4] = {0.f,0.f,0.f,0.f};
  const u16* bp = biasbuf + (((size_t)(b*H_ + h)*N_) + n0 + 16*w)*N_ + ln;

  for (int mt = 0; mt < 8; mt++){
    __syncthreads();
    {
      int r = tid >> 2, cb = (tid & 3)*16;
      const u16* kp = qkv + (size_t)(b*N_ + mt*64 + r)*3072 + 1024 + h*64 + cb;
      uint4 k0 = *(const uint4*)kp, k1 = *(const uint4*)(kp+8);
      uint4* kd = (uint4*)&Ks[r*72 + cb];
      kd[0] = k0; kd[1] = k1;
      const u16* vp = qkv + (size_t)(b*N_ + mt*64 + r)*3072 + 2048 + h*64 + cb;
      uint4 v0 = *(const uint4*)vp, v1 = *(const uint4*)(vp+8);
      u16 ve[16];
      *(uint4*)&ve[0] = v0; *(uint4*)&ve[8] = v1;
      #pragma unroll
      for (int j=0;j<16;j++) Vt[(cb+j)*72 + r] = ve[j];
    }
    __syncthreads();

    u16 bl[4][4];
    #pragma unroll
    for (int cs=0; cs<4; cs++)
      #pragma unroll
      for (int i=0;i<4;i++)
        bl[cs][i] = bp[(size_t)(quad*4+i)*N_ + mt*64 + 16*cs];

    f32x4 s[4];
    #pragma unroll
    for (int cs=0; cs<4; cs++){
      bf16x8 k0f = *(const bf16x8*)&Ks[(16*cs+ln)*72 + quad*8];
      bf16x8 k1f = *(const bf16x8*)&Ks[(16*cs+ln)*72 + 32 + quad*8];
      f32x4 z = {};
      z = __builtin_amdgcn_mfma_f32_16x16x32_bf16(qf[0], k0f, z, 0,0,0);
      z = __builtin_amdgcn_mfma_f32_16x16x32_bf16(qf[1], k1f, z, 0,0,0);
      s[cs] = z;
    }
    #pragma unroll
    for (int cs=0; cs<4; cs++)
      #pragma unroll
      for (int i=0;i<4;i++)
        s[cs][i] = s[cs][i]*0.125f + b2f(bl[cs][i]);

    #pragma unroll
    for (int i=0;i<4;i++){
      float tm = fmaxf(fmaxf(s[0][i], s[1][i]), fmaxf(s[2][i], s[3][i]));
      #pragma unroll
      for (int o=1;o<16;o<<=1) tm = fmaxf(tm, __shfl_xor(tm, o));
      float nm = fmaxf(rmax[i], tm);
      float alpha = __expf(rmax[i] - nm);
      rmax[i] = nm;
      float ps = 0.f;
      #pragma unroll
      for (int cs=0; cs<4; cs++){
        float p = __expf(s[cs][i] - nm);
        s[cs][i] = p; ps += p;
      }
      #pragma unroll
      for (int o=1;o<16;o<<=1) ps += __shfl_xor(ps, o);
      rsum[i] = rsum[i]*alpha + ps;
      #pragma unroll
      for (int ds=0; ds<4; ds++) oacc[ds][i] *= alpha;
    }

    #pragma unroll
    for (int cs=0; cs<4; cs++)
      #pragma unroll
      for (int i=0;i<4;i++)
        Ps[w*1152 + (quad*4+i)*72 + 16*cs + ln] = f2b(s[cs][i]);

    bf16x8 pf0 = *(const bf16x8*)&Ps[w*1152 + ln*72 + quad*8];
    bf16x8 pf1 = *(const bf16x8*)&Ps[w*1152 + ln*72 + 32 + quad*8];
    #pragma unroll
    for (int ds=0; ds<4; ds++){
      bf16x8 v0f = *(const bf16x8*)&Vt[(16*ds+ln)*72 + quad*8];
      bf16x8 v1f = *(const bf16x8*)&Vt[(16*ds+ln)*72 + 32 + quad*8];
      oacc[ds] = __builtin_amdgcn_mfma_f32_16x16x32_bf16(pf0, v0f, oacc[ds], 0,0,0);
      oacc[ds] = __builtin_amdgcn_mfma_f32_16x16x32_bf16(pf1, v1f, oacc[ds], 0,0,0);
    }
  }

  #pragma unroll
  for (int i=0;i<4;i++){
    float inv = 1.f / rsum[i];
    int r = b*N_ + n0 + 16*w + quad*4 + i;
    #pragma unroll
    for (int ds=0; ds<4; ds++)
      attn_out[(size_t)r*D_ + h*64 + 16*ds + ln] = f2b(oacc[ds][i]*inv);
  }
}

extern "C" void kernel_launch(void* const* d_in, const int* in_sizes, int n_in,
                              void* d_out, int out_size, void* d_ws, size_t ws_size,
                              hipStream_t stream) {
  const float* x      = (const float*)d_in[0];
  const float* t_emb  = (const float*)d_in[1];
  const float* rel    = (const float*)d_in[2];
  const int*   amask  = (const int*)d_in[3];
  const float* w_ada  = (const float*)d_in[4];
  const float* b_ada  = (const float*)d_in[5];
  const float* g1     = (const float*)d_in[6];
  const float* beta1  = (const float*)d_in[7];
  const float* g2     = (const float*)d_in[8];
  const float* beta2  = (const float*)d_in[9];
  const float* w_qkv  = (const float*)d_in[10];
  const float* b_qkv  = (const float*)d_in[11];
  const float* w_proj = (const float*)d_in[12];
  const float* b_proj = (const float*)d_in[13];
  const float* w_rp1  = (const float*)d_in[14];
  const float* b_rp1  = (const float*)d_in[15];
  const float* w_rp2  = (const float*)d_in[16];
  const float* b_rp2  = (const float*)d_in[17];
  const float* w_fc1  = (const float*)d_in[18];
  const float* b_fc1  = (const float*)d_in[19];
  const float* w_fc2  = (const float*)d_in[20];
  const float* b_fc2  = (const float*)d_in[21];
  float* outp = (float*)d_out;

  const size_t MB = 1u<<20;
  char* wsb = (char*)d_ws;
  float* mod   = (float*)(wsb);
  u16*  xn     = (u16*) (wsb + 131072);
  float* xm    = (float*)(wsb + 131072 + 4*MB);
  u16*  wqkvb  = (u16*) (wsb + 131072 + 12*MB);
  u16*  wprojb = (u16*) (wsb + 131072 + 18*MB);
  u16*  partb  = (u16*) (wsb + 131072 + 20*MB);       // 8 MB (2 x [M,1024])
  char*  S     = wsb + 131072 + 28*MB;
  u16*  qkvb   = (u16*)(S);                           // [M,3072] 12 MB
  u16*  biasb  = (u16*)(S + 12*MB);                   // [B,H,N,N] 32 MB
  u16*  projp23= (u16*)(S);                           // PROJ partials 2,3 (qkvb dead)
  u16*  hb     = (u16*)(S);                           // [M,4096] 16 MB (phase B)
  u16*  wfc1b  = (u16*)(S + 16*MB);
  u16*  wfc2b  = (u16*)(S + 24*MB);
  u16*  fc2p23 = (u16*)(S + 32*MB);                   // FC2 partials 2,3 (8 MB)

  k_cvt2<<<2048, 256, 0, stream>>>(w_qkv, wqkvb, 1536, w_proj, wprojb);
  k_mod<<<dim3(6*D_/256, B_), 256, 0, stream>>>(t_emb, w_ada, b_ada, mod);
  k_lnmod<<<M_, 256, 0, stream>>>(x, g1, beta1, mod, 0, 1, xn);
  // QKV: 64x128 tiles, direct epilogue with bias -> qkvb
  k_gemm64<EPI_PLAIN><<<dim3(3072/128, M_/64), 256, 0, stream>>>(
      xn, wqkvb, b_qkv, D_, 3072, qkvb);
  k_bias<<<dim3(2, N_, B_), 256, 0, stream>>>(rel, amask, w_rp1, b_rp1, w_rp2, b_rp2, biasb);
  k_attn<<<dim3(8, H_, B_), 256, 0, stream>>>(qkvb, biasb, xn);
  k_cvt2<<<4096, 256, 0, stream>>>(w_fc1, wfc1b, 2048, w_fc2, wfc2b);
  // PROJ split-K x4 -> partials -> fused reduce+LN2 -> xm, xn
  k_gemm<<<dim3(D_/128, M_/128, 4), 256, 0, stream>>>(
      xn, wprojb, D_, D_/4, D_, partb, projp23);
  k_redln<<<M_, 256, 0, stream>>>(partb, projp23, b_proj, mod, x, g2, beta2, xm, xn);
  // FC1: 64x128 tiles, fused GELU -> hb
  k_gemm64<EPI_GELU><<<dim3(HID_/128, M_/64), 256, 0, stream>>>(
      xn, wfc1b, b_fc1, D_, HID_, hb);
  // FC2 split-K x4 -> partials -> reduce -> out
  k_gemm<<<dim3(D_/128, M_/128, 4), 256, 0, stream>>>(
      hb, wfc2b, HID_, HID_/4, D_, partb, fc2p23);
  k_red4<5><<<2048, 256, 0, stream>>>(partb, fc2p23, b_fc2, mod, xm, outp);
}